// Round 3
// baseline (6001.475 us; speedup 1.0000x reference)
//
#include <hip/hip_runtime.h>

typedef unsigned short u16;
typedef u16 u16x8 __attribute__((ext_vector_type(8)));
typedef __bf16 bf16x8 __attribute__((ext_vector_type(8)));
typedef float f32x4 __attribute__((ext_vector_type(4)));

#define TTOK 32768
#define HD 512
#define FFD 2048
#define SLEN 64

__device__ __forceinline__ float b2f(u16 u) {
  union { float f; unsigned int i; } v; v.i = ((unsigned int)u) << 16; return v.f;
}
__device__ __forceinline__ u16 f2b(float f) {
  union { float f; unsigned int i; } v; v.f = f;
  unsigned int i = v.i;
  return (u16)((i + 0x7FFFu + ((i >> 16) & 1u)) >> 16);  // RNE
}

__device__ __forceinline__ void gload16(const u16* g, u16* l) {
  __builtin_amdgcn_global_load_lds((const __attribute__((address_space(1))) void*)g,
                                   (__attribute__((address_space(3))) void*)l,
                                   16, 0, 0);
}

__device__ __forceinline__ f32x4 mfma16(bf16x8 a, bf16x8 b, f32x4 c) {
  return __builtin_amdgcn_mfma_f32_16x16x32_bf16(a, b, c, 0, 0, 0);
}

// ---------------- positional encoding table [S,H] f32 ----------------
__global__ __launch_bounds__(256) void pe_kernel(float* __restrict__ pe) {
  int idx = blockIdx.x * 256 + threadIdx.x;     // 64*512 = 32768
  int s = idx >> 9, h = idx & 511;
  float e2i = (float)(h & ~1);
  float ang = (float)s * powf(10000.0f, -e2i * (1.0f / 512.0f));
  pe[idx] = (h & 1) ? cosf(ang) : sinf(ang);
}

// ---------------- embedding (f32) + PE (f32) -> bf16 ----------------
__global__ __launch_bounds__(256) void embed_kernel(
    const int* __restrict__ ids, const float* __restrict__ emb,
    const float* __restrict__ pe, u16* __restrict__ outB) {
  int chunk = blockIdx.x * 256 + threadIdx.x;   // T*H/8 = 2097152
  int t = chunk >> 6;
  int c8 = (chunk & 63) * 8;
  int s = t & (SLEN - 1);
  int id = ids[t];
  const float* e = emb + (size_t)id * HD + c8;
  const float* p = pe + s * HD + c8;
  f32x4 e0 = *(const f32x4*)e, e1 = *(const f32x4*)(e + 4);
  f32x4 p0 = *(const f32x4*)p, p1 = *(const f32x4*)(p + 4);
  u16x8 ob;
  #pragma unroll
  for (int i = 0; i < 4; ++i) {
    ob[i]     = f2b(e0[i] + p0[i]);
    ob[4 + i] = f2b(e1[i] + p1[i]);
  }
  *(u16x8*)(outB + (size_t)t * HD + c8) = ob;
}

// ---------------- residual + layernorm (bf16 in, f32 params, bf16/f32 out) ----
// outB may alias A (in-place): each thread reads its 8 elems before any write.
template<int F32OUT>
__global__ __launch_bounds__(256) void ln_kernel(
    const u16* A, const u16* __restrict__ Z,
    const float* __restrict__ g, const float* __restrict__ b,
    u16* outB, float* outF) {
  int row = blockIdx.x * 4 + (threadIdx.x >> 6);
  int lane = threadIdx.x & 63;
  size_t base = (size_t)row * HD + lane * 8;
  u16x8 av = *(const u16x8*)(A + base);
  u16x8 zv = *(const u16x8*)(Z + base);
  float x[8];
  float s = 0.f;
  #pragma unroll
  for (int i = 0; i < 8; ++i) { x[i] = b2f(av[i]) + b2f(zv[i]); s += x[i]; }
  #pragma unroll
  for (int off = 32; off; off >>= 1) s += __shfl_xor(s, off);
  float m = s * (1.0f / HD);
  float vs = 0.f;
  #pragma unroll
  for (int i = 0; i < 8; ++i) { float d = x[i] - m; vs += d * d; }
  #pragma unroll
  for (int off = 32; off; off >>= 1) vs += __shfl_xor(vs, off);
  float rstd = rsqrtf(vs * (1.0f / HD) + 1e-5f);
  f32x4 g0 = *(const f32x4*)(g + lane * 8), g1 = *(const f32x4*)(g + lane * 8 + 4);
  f32x4 b0 = *(const f32x4*)(b + lane * 8), b1 = *(const f32x4*)(b + lane * 8 + 4);
  float o[8];
  #pragma unroll
  for (int i = 0; i < 4; ++i) {
    o[i]     = (x[i] - m) * rstd * g0[i] + b0[i];
    o[4 + i] = (x[4 + i] - m) * rstd * g1[i] + b1[i];
  }
  if (F32OUT) {
    f32x4 o0, o1;
    #pragma unroll
    for (int i = 0; i < 4; ++i) { o0[i] = o[i]; o1[i] = o[4 + i]; }
    *(f32x4*)(outF + base) = o0;
    *(f32x4*)(outF + base + 4) = o1;
  } else {
    u16x8 ob;
    #pragma unroll
    for (int i = 0; i < 8; ++i) ob[i] = f2b(o[i]);
    *(u16x8*)(outB + base) = ob;
  }
}

// ---- bf16 NT GEMM: C[M,N] = A[M,K](bf16) @ Bw[N,K](f32)^T (+f32 bias) -> bf16 ----
// 128x128 tile, BK=64, 256 threads (4 waves 2x2), mfma 16x16x32.
// A staged via global_load_lds w16; B reg-staged with f32->bf16 convert.
template<int BIAS>
__global__ __launch_bounds__(256) void gemm_nt(
    const u16* __restrict__ A, const float* __restrict__ Bw,
    const float* __restrict__ bias, u16* __restrict__ Cb,
    int M, int N, int K) {
  __shared__ u16 As[128 * 64];
  __shared__ u16 Bs[128 * 64];
  const int tid = threadIdx.x;
  const int lane = tid & 63, w = tid >> 6;
  const int wm = w >> 1, wn = w & 1;
  const int bm = blockIdx.x * 128, bn = blockIdx.y * 128;

  f32x4 acc[4][4] = {};

  const u16* Ab = A + (size_t)bm * K;
  const float* Bb = Bw + (size_t)bn * K;
  const int r8 = lane >> 3;            // 0..7
  const int c8 = (lane & 7) * 8;       // 0..56
  const int l15 = lane & 15, l16 = (lane >> 4) * 8;

  for (int kt = 0; kt < K; kt += 64) {
    #pragma unroll
    for (int it = 0; it < 4; ++it) {
      int row = w * 32 + it * 8;       // wave-uniform LDS base row
      gload16(Ab + (size_t)(row + r8) * K + kt + c8, As + row * 64);
    }
    #pragma unroll
    for (int it = 0; it < 4; ++it) {
      int row = w * 32 + it * 8 + r8;
      const float* src = Bb + (size_t)row * K + kt + c8;
      f32x4 x0 = *(const f32x4*)src, x1 = *(const f32x4*)(src + 4);
      u16x8 pk;
      #pragma unroll
      for (int i = 0; i < 4; ++i) { pk[i] = f2b(x0[i]); pk[4 + i] = f2b(x1[i]); }
      *(u16x8*)&Bs[row * 64 + c8] = pk;
    }
    __syncthreads();
    #pragma unroll
    for (int kk = 0; kk < 2; ++kk) {
      bf16x8 af[4], bfr[4];
      #pragma unroll
      for (int i = 0; i < 4; ++i)
        af[i] = *(const bf16x8*)&As[(wm * 64 + i * 16 + l15) * 64 + kk * 32 + l16];
      #pragma unroll
      for (int j = 0; j < 4; ++j)
        bfr[j] = *(const bf16x8*)&Bs[(wn * 64 + j * 16 + l15) * 64 + kk * 32 + l16];
      #pragma unroll
      for (int i = 0; i < 4; ++i)
        #pragma unroll
        for (int j = 0; j < 4; ++j)
          acc[i][j] = mfma16(af[i], bfr[j], acc[i][j]);
    }
    __syncthreads();
  }

  #pragma unroll
  for (int j = 0; j < 4; ++j) {
    int col = bn + wn * 64 + j * 16 + l15;
    float bv = 0.f;
    if (BIAS) bv = bias[col];
    #pragma unroll
    for (int i = 0; i < 4; ++i) {
      int row0 = bm + wm * 64 + i * 16 + (lane >> 4) * 4;
      #pragma unroll
      for (int r = 0; r < 4; ++r)
        Cb[(size_t)(row0 + r) * N + col] = f2b(acc[i][j][r] + bv);
    }
  }
}

// ---------------- attention: one block per (b, head), S=64, DK=64 ----------------
// Q,K,V,O bf16 [T,H] layout, head slice = cols h*64..h*64+63. O may alias Q
// (all Q reads precede the single __syncthreads; O writes follow; blocks own
// disjoint (b,h) slices).
template<int CAUSAL>
__global__ __launch_bounds__(256) void attn_kernel(
    const u16* Q, const u16* __restrict__ Kb, const u16* __restrict__ Vb,
    const int* __restrict__ mask, u16* O) {
  __shared__ u16 Ks[64 * 72];
  __shared__ u16 Vt[64 * 72];      // transposed: Vt[d][k]
  __shared__ u16 Ps[4][16 * 72];
  const int bh = blockIdx.x;
  const int b = bh >> 3, h = bh & 7;
  const int h0 = h * 64;
  const int tid = threadIdx.x, lane = tid & 63, w = tid >> 6;
  const size_t base = (size_t)b * 64 * HD + h0;
  const int l15 = lane & 15, l16 = (lane >> 4) * 8;

  { // stage K and V^T
    int r = tid >> 2;
    int c = (tid & 3) * 16;
    const u16* ksrc = Kb + base + (size_t)r * HD + c;
    *(u16x8*)&Ks[r * 72 + c]     = *(const u16x8*)ksrc;
    *(u16x8*)&Ks[r * 72 + c + 8] = *(const u16x8*)(ksrc + 8);
    const u16* vsrc = Vb + base + (size_t)r * HD + c;
    u16x8 t0 = *(const u16x8*)vsrc;
    u16x8 t1 = *(const u16x8*)(vsrc + 8);
    #pragma unroll
    for (int i = 0; i < 8; ++i) {
      Vt[(c + i) * 72 + r]     = t0[i];
      Vt[(c + 8 + i) * 72 + r] = t1[i];
    }
  }
  const int qrow = w * 16 + l15;
  const u16* qp = Q + base + (size_t)qrow * HD;
  bf16x8 qf0 = *(const bf16x8*)&qp[l16];
  bf16x8 qf1 = *(const bf16x8*)&qp[32 + l16];
  __syncthreads();

  // scores = Q K^T
  f32x4 sc[4] = {};
  #pragma unroll
  for (int nf = 0; nf < 4; ++nf) {
    bf16x8 k0 = *(const bf16x8*)&Ks[(nf * 16 + l15) * 72 + l16];
    bf16x8 k1 = *(const bf16x8*)&Ks[(nf * 16 + l15) * 72 + 32 + l16];
    sc[nf] = mfma16(qf0, k0, sc[nf]);
    sc[nf] = mfma16(qf1, k1, sc[nf]);
  }
  // mask + scale; lane holds rows q=w*16+(lane>>4)*4+r, cols k=nf*16+(lane&15)
  int mk[4];
  #pragma unroll
  for (int nf = 0; nf < 4; ++nf) mk[nf] = mask[b * 64 + nf * 16 + l15];
  float pv[4][4];
  #pragma unroll
  for (int r = 0; r < 4; ++r) {
    int q = w * 16 + (lane >> 4) * 4 + r;
    #pragma unroll
    for (int nf = 0; nf < 4; ++nf) {
      int k = nf * 16 + l15;
      bool kp = (mk[nf] != 0);
      if (CAUSAL) kp = kp && (k <= q);
      pv[r][nf] = kp ? sc[nf][r] * 0.125f : -1e9f;
    }
  }
  // softmax per row across the 16-lane group
  #pragma unroll
  for (int r = 0; r < 4; ++r) {
    float mx = fmaxf(fmaxf(pv[r][0], pv[r][1]), fmaxf(pv[r][2], pv[r][3]));
    #pragma unroll
    for (int off = 1; off < 16; off <<= 1) mx = fmaxf(mx, __shfl_xor(mx, off));
    float sum = 0.f;
    #pragma unroll
    for (int nf = 0; nf < 4; ++nf) { pv[r][nf] = __expf(pv[r][nf] - mx); sum += pv[r][nf]; }
    #pragma unroll
    for (int off = 1; off < 16; off <<= 1) sum += __shfl_xor(sum, off);
    float inv = 1.0f / sum;
    #pragma unroll
    for (int nf = 0; nf < 4; ++nf) pv[r][nf] *= inv;
  }
  // P -> LDS (per-wave private region)
  #pragma unroll
  for (int r = 0; r < 4; ++r) {
    int q = (lane >> 4) * 4 + r;
    #pragma unroll
    for (int nf = 0; nf < 4; ++nf)
      Ps[w][q * 72 + nf * 16 + l15] = f2b(pv[r][nf]);
  }
  // O = P V
  f32x4 oacc[4] = {};
  #pragma unroll
  for (int kk = 0; kk < 2; ++kk) {
    bf16x8 pa = *(const bf16x8*)&Ps[w][l15 * 72 + kk * 32 + l16];
    #pragma unroll
    for (int df = 0; df < 4; ++df) {
      bf16x8 vf = *(const bf16x8*)&Vt[(df * 16 + l15) * 72 + kk * 32 + l16];
      oacc[df] = mfma16(pa, vf, oacc[df]);
    }
  }
  #pragma unroll
  for (int df = 0; df < 4; ++df) {
    int col = h0 + df * 16 + l15;
    #pragma unroll
    for (int r = 0; r < 4; ++r) {
      int t = b * 64 + w * 16 + (lane >> 4) * 4 + r;
      O[(size_t)t * HD + col] = f2b(oacc[df][r]);
    }
  }
}

// ---------------- host side ----------------
extern "C" void kernel_launch(void* const* d_in, const int* in_sizes, int n_in,
                              void* d_out, int out_size, void* d_ws, size_t ws_size,
                              hipStream_t stream) {
  const int* src_ids    = (const int*)d_in[0];
  const int* tgt_ids    = (const int*)d_in[1];
  const int* src_mask   = (const int*)d_in[2];
  const int* tgt_mask   = (const int*)d_in[3];
  const float* src_emb  = (const float*)d_in[4];
  const float* tgt_emb  = (const float*)d_in[5];
  const float* enc_wq = (const float*)d_in[6];
  const float* enc_wk = (const float*)d_in[7];
  const float* enc_wv = (const float*)d_in[8];
  const float* enc_wo = (const float*)d_in[9];
  const float* enc_g  = (const float*)d_in[10];
  const float* enc_b  = (const float*)d_in[11];
  const float* fc1w = (const float*)d_in[12];
  const float* fc1b = (const float*)d_in[13];
  const float* fc2w = (const float*)d_in[14];
  const float* fc2b = (const float*)d_in[15];
  const float* mwq = (const float*)d_in[16];
  const float* mwk = (const float*)d_in[17];
  const float* mwv = (const float*)d_in[18];
  const float* mwo = (const float*)d_in[19];
  const float* cwq = (const float*)d_in[20];
  const float* cwo = (const float*)d_in[21];
  const float* dec_g = (const float*)d_in[22];
  const float* dec_b = (const float*)d_in[23];
  const float* dfw = (const float*)d_in[24];
  const float* dfb = (const float*)d_in[25];
  float* outF = (float*)d_out;

  // workspace: pe table + 6 bf16 [TTOK,HD] buffers = 192.1 MB (fits: round-2 ran)
  constexpr size_t SZ_PE = (size_t)SLEN * HD * 4;       // 128 KB
  constexpr size_t SZ_B  = (size_t)TTOK * HD * 2;       // 32 MB
  constexpr size_t NEED  = SZ_PE + 6 * SZ_B;
  if (ws_size < NEED) return;  // clean failure instead of fault

  char* ws = (char*)d_ws;
  float* pe = (float*)ws;
  u16* cur = (u16*)(ws + SZ_PE);
  u16* t0  = (u16*)(ws + SZ_PE + 1 * SZ_B);
  u16* t1  = (u16*)(ws + SZ_PE + 2 * SZ_B);  // also decoder V
  u16* ke  = (u16*)(ws + SZ_PE + 3 * SZ_B);
  u16* ve  = (u16*)(ws + SZ_PE + 4 * SZ_B);
  u16* x0  = (u16*)(ws + SZ_PE + 5 * SZ_B);  // enc FFN chunk [8192,2048] / decoder K

  dim3 blk(256);
  dim3 g512(TTOK / 128, HD / 128);           // [32768 x 512] gemm
  dim3 gf1(8192 / 128, FFD / 128);           // fc1 chunk [8192 x 2048]
  dim3 gf2(8192 / 128, HD / 128);            // fc2 chunk [8192 x 512]

  pe_kernel<<<128, blk, 0, stream>>>(pe);

  // ---------------- encoder ----------------
  embed_kernel<<<8192, blk, 0, stream>>>(src_ids, src_emb, pe, cur);
  for (int l = 0; l < 6; ++l) {
    const float* wq = enc_wq + (size_t)l * HD * HD;
    const float* wk = enc_wk + (size_t)l * HD * HD;
    const float* wv = enc_wv + (size_t)l * HD * HD;
    const float* wo = enc_wo + (size_t)l * HD * HD;
    const float* g  = enc_g + (size_t)l * HD;
    const float* bb = enc_b + (size_t)l * HD;
    const float* w1 = fc1w + (size_t)l * FFD * HD;
    const float* b1 = fc1b + (size_t)l * FFD;
    const float* w2 = fc2w + (size_t)l * HD * FFD;
    const float* b2 = fc2b + (size_t)l * HD;

    gemm_nt<0><<<g512, blk, 0, stream>>>(cur, wq, nullptr, t0, TTOK, HD, HD);
    gemm_nt<0><<<g512, blk, 0, stream>>>(cur, wk, nullptr, ke, TTOK, HD, HD);
    gemm_nt<0><<<g512, blk, 0, stream>>>(cur, wv, nullptr, ve, TTOK, HD, HD);
    attn_kernel<0><<<4096, blk, 0, stream>>>(t0, ke, ve, src_mask, t0);
    gemm_nt<0><<<g512, blk, 0, stream>>>(t0, wo, nullptr, t1, TTOK, HD, HD);
    ln_kernel<0><<<8192, blk, 0, stream>>>(cur, t1, g, bb, cur, nullptr);
    for (int c = 0; c < 4; ++c) {            // chunked FFN: 8192 tokens/chunk
      const u16* ac = cur + (size_t)c * 8192 * HD;
      u16* zc = t1 + (size_t)c * 8192 * HD;
      gemm_nt<1><<<gf1, blk, 0, stream>>>(ac, w1, b1, x0, 8192, FFD, HD);
      gemm_nt<1><<<gf2, blk, 0, stream>>>(x0, w2, b2, zc, 8192, HD, FFD);
    }
    ln_kernel<0><<<8192, blk, 0, stream>>>(cur, t1, g, bb, cur, nullptr);
  }

  // ---------------- decoder ----------------
  embed_kernel<<<8192, blk, 0, stream>>>(tgt_ids, tgt_emb, pe, cur);
  for (int l = 0; l < 6; ++l) {
    const float* wq = mwq + (size_t)l * HD * HD;
    const float* wk = mwk + (size_t)l * HD * HD;
    const float* wv = mwv + (size_t)l * HD * HD;
    const float* wo = mwo + (size_t)l * HD * HD;
    const float* cq = cwq + (size_t)l * HD * HD;
    const float* co = cwo + (size_t)l * HD * HD;
    const float* g  = dec_g + (size_t)l * HD;
    const float* bb = dec_b + (size_t)l * HD;
    const float* fw = dfw + (size_t)l * HD * HD;
    const float* fb = dfb + (size_t)l * HD;

    gemm_nt<0><<<g512, blk, 0, stream>>>(cur, wq, nullptr, t0, TTOK, HD, HD);
    gemm_nt<0><<<g512, blk, 0, stream>>>(cur, wk, nullptr, x0, TTOK, HD, HD);
    gemm_nt<0><<<g512, blk, 0, stream>>>(cur, wv, nullptr, t1, TTOK, HD, HD);
    attn_kernel<1><<<4096, blk, 0, stream>>>(t0, x0, t1, tgt_mask, t0);
    gemm_nt<0><<<g512, blk, 0, stream>>>(t0, wo, nullptr, t1, TTOK, HD, HD);
    ln_kernel<0><<<8192, blk, 0, stream>>>(cur, t1, g, bb, cur, nullptr);

    gemm_nt<0><<<g512, blk, 0, stream>>>(cur, cq, nullptr, t0, TTOK, HD, HD);
    attn_kernel<1><<<4096, blk, 0, stream>>>(t0, ke, ve, tgt_mask, t0);
    gemm_nt<0><<<g512, blk, 0, stream>>>(t0, co, nullptr, t1, TTOK, HD, HD);
    ln_kernel<0><<<8192, blk, 0, stream>>>(cur, t1, g, bb, cur, nullptr);

    gemm_nt<1><<<g512, blk, 0, stream>>>(cur, fw, fb, t1, TTOK, HD, HD);
    if (l == 5)
      ln_kernel<1><<<8192, blk, 0, stream>>>(cur, t1, g, bb, nullptr, outF);
    else
      ln_kernel<0><<<8192, blk, 0, stream>>>(cur, t1, g, bb, cur, nullptr);
  }
  (void)in_sizes; (void)n_in; (void)out_size;
}

// Round 4
// 4637.913 us; speedup vs baseline: 1.2940x; 1.2940x over previous
//
#include <hip/hip_runtime.h>

typedef unsigned short u16;
typedef u16 u16x8 __attribute__((ext_vector_type(8)));
typedef __bf16 bf16x8 __attribute__((ext_vector_type(8)));
typedef float f32x4 __attribute__((ext_vector_type(4)));

#define TTOK 32768
#define HD 512
#define FFD 2048
#define SLEN 64
#define EW 262144            // 512*512 elems

__device__ __forceinline__ float b2f(u16 u) {
  union { float f; unsigned int i; } v; v.i = ((unsigned int)u) << 16; return v.f;
}
__device__ __forceinline__ u16 f2b(float f) {
  union { float f; unsigned int i; } v; v.f = f;
  unsigned int i = v.i;
  return (u16)((i + 0x7FFFu + ((i >> 16) & 1u)) >> 16);  // RNE
}

__device__ __forceinline__ void gload16(const u16* g, u16* l) {
  __builtin_amdgcn_global_load_lds((const __attribute__((address_space(1))) void*)g,
                                   (__attribute__((address_space(3))) void*)l,
                                   16, 0, 0);
}

__device__ __forceinline__ f32x4 mfma16(bf16x8 a, bf16x8 b, f32x4 c) {
  return __builtin_amdgcn_mfma_f32_16x16x32_bf16(a, b, c, 0, 0, 0);
}

// ---------------- positional encoding table [S,H] f32 ----------------
__global__ __launch_bounds__(256) void pe_kernel(float* __restrict__ pe) {
  int idx = blockIdx.x * 256 + threadIdx.x;     // 64*512 = 32768
  int s = idx >> 9, h = idx & 511;
  float e2i = (float)(h & ~1);
  float ang = (float)s * powf(10000.0f, -e2i * (1.0f / 512.0f));
  pe[idx] = (h & 1) ? cosf(ang) : sinf(ang);
}

// ------------- weight convert f32 -> bf16, per-layer strided dest -------------
// src: [6, npl] f32 contiguous. dst layer l at dst + l*dstride + r.
__global__ __launch_bounds__(256) void wconv_kernel(
    const float* __restrict__ src, u16* __restrict__ dst,
    unsigned int npl, unsigned int dstride) {
  size_t i = ((size_t)blockIdx.x * 256 + threadIdx.x) * 8;  // over 6*npl
  unsigned int l = (unsigned int)(i / npl);
  unsigned int r = (unsigned int)(i - (size_t)l * npl);
  f32x4 a = *(const f32x4*)(src + i), b = *(const f32x4*)(src + i + 4);
  u16x8 o;
  #pragma unroll
  for (int k = 0; k < 4; ++k) { o[k] = f2b(a[k]); o[4 + k] = f2b(b[k]); }
  *(u16x8*)(dst + (size_t)l * dstride + r) = o;
}

// ---------------- embedding (f32) + PE (f32) -> bf16 ----------------
__global__ __launch_bounds__(256) void embed_kernel(
    const int* __restrict__ ids, const float* __restrict__ emb,
    const float* __restrict__ pe, u16* __restrict__ outB) {
  int chunk = blockIdx.x * 256 + threadIdx.x;   // T*H/8 = 2097152
  int t = chunk >> 6;
  int c8 = (chunk & 63) * 8;
  int s = t & (SLEN - 1);
  int id = ids[t];
  const float* e = emb + (size_t)id * HD + c8;
  const float* p = pe + s * HD + c8;
  f32x4 e0 = *(const f32x4*)e, e1 = *(const f32x4*)(e + 4);
  f32x4 p0 = *(const f32x4*)p, p1 = *(const f32x4*)(p + 4);
  u16x8 ob;
  #pragma unroll
  for (int i = 0; i < 4; ++i) {
    ob[i]     = f2b(e0[i] + p0[i]);
    ob[4 + i] = f2b(e1[i] + p1[i]);
  }
  *(u16x8*)(outB + (size_t)t * HD + c8) = ob;
}

// ---------------- residual + layernorm (bf16 in, f32 params) ----------------
// outB may alias A (in-place): each thread reads its 8 elems before any write.
template<int F32OUT>
__global__ __launch_bounds__(256) void ln_kernel(
    const u16* A, const u16* __restrict__ Z,
    const float* __restrict__ g, const float* __restrict__ b,
    u16* outB, float* outF) {
  int row = blockIdx.x * 4 + (threadIdx.x >> 6);
  int lane = threadIdx.x & 63;
  size_t base = (size_t)row * HD + lane * 8;
  u16x8 av = *(const u16x8*)(A + base);
  u16x8 zv = *(const u16x8*)(Z + base);
  float x[8];
  float s = 0.f;
  #pragma unroll
  for (int i = 0; i < 8; ++i) { x[i] = b2f(av[i]) + b2f(zv[i]); s += x[i]; }
  #pragma unroll
  for (int off = 32; off; off >>= 1) s += __shfl_xor(s, off);
  float m = s * (1.0f / HD);
  float vs = 0.f;
  #pragma unroll
  for (int i = 0; i < 8; ++i) { float d = x[i] - m; vs += d * d; }
  #pragma unroll
  for (int off = 32; off; off >>= 1) vs += __shfl_xor(vs, off);
  float rstd = rsqrtf(vs * (1.0f / HD) + 1e-5f);
  f32x4 g0 = *(const f32x4*)(g + lane * 8), g1 = *(const f32x4*)(g + lane * 8 + 4);
  f32x4 b0 = *(const f32x4*)(b + lane * 8), b1 = *(const f32x4*)(b + lane * 8 + 4);
  float o[8];
  #pragma unroll
  for (int i = 0; i < 4; ++i) {
    o[i]     = (x[i] - m) * rstd * g0[i] + b0[i];
    o[4 + i] = (x[4 + i] - m) * rstd * g1[i] + b1[i];
  }
  if (F32OUT) {
    f32x4 o0, o1;
    #pragma unroll
    for (int i = 0; i < 4; ++i) { o0[i] = o[i]; o1[i] = o[4 + i]; }
    *(f32x4*)(outF + base) = o0;
    *(f32x4*)(outF + base + 4) = o1;
  } else {
    u16x8 ob;
    #pragma unroll
    for (int i = 0; i < 8; ++i) ob[i] = f2b(o[i]);
    *(u16x8*)(outB + base) = ob;
  }
}

// ---- bf16 NT GEMM: C[M,N] = A[M,K] @ Bw[N,K]^T (+f32 bias) -> bf16 ----
// 128x128 tile, BK=64, 256 threads (4 waves 2x2), mfma 16x16x32.
// Both operands staged via global_load_lds w16. A row stride lda, C row stride ldc.
template<int BIAS>
__global__ __launch_bounds__(256) void gemm_nt(
    const u16* __restrict__ A, const u16* __restrict__ Bw,
    const float* __restrict__ bias, u16* __restrict__ Cb,
    int M, int N, int K, int lda, int ldc) {
  __shared__ u16 As[128 * 64];
  __shared__ u16 Bs[128 * 64];
  const int tid = threadIdx.x;
  const int lane = tid & 63, w = tid >> 6;
  const int wm = w >> 1, wn = w & 1;
  const int bm = blockIdx.x * 128, bn = blockIdx.y * 128;

  f32x4 acc[4][4] = {};

  const u16* Ab = A + (size_t)bm * lda;
  const u16* Bb = Bw + (size_t)bn * K;
  const int r8 = lane >> 3;            // 0..7
  const int c8 = (lane & 7) * 8;       // 0..56
  const int l15 = lane & 15, l16 = (lane >> 4) * 8;

  for (int kt = 0; kt < K; kt += 64) {
    #pragma unroll
    for (int it = 0; it < 4; ++it) {
      int row = w * 32 + it * 8;       // wave-uniform LDS base row
      gload16(Ab + (size_t)(row + r8) * lda + kt + c8, As + row * 64);
      gload16(Bb + (size_t)(row + r8) * K   + kt + c8, Bs + row * 64);
    }
    __syncthreads();
    #pragma unroll
    for (int kk = 0; kk < 2; ++kk) {
      bf16x8 af[4], bfr[4];
      #pragma unroll
      for (int i = 0; i < 4; ++i)
        af[i] = *(const bf16x8*)&As[(wm * 64 + i * 16 + l15) * 64 + kk * 32 + l16];
      #pragma unroll
      for (int j = 0; j < 4; ++j)
        bfr[j] = *(const bf16x8*)&Bs[(wn * 64 + j * 16 + l15) * 64 + kk * 32 + l16];
      #pragma unroll
      for (int i = 0; i < 4; ++i)
        #pragma unroll
        for (int j = 0; j < 4; ++j)
          acc[i][j] = mfma16(af[i], bfr[j], acc[i][j]);
    }
    __syncthreads();
  }

  #pragma unroll
  for (int j = 0; j < 4; ++j) {
    int col = bn + wn * 64 + j * 16 + l15;
    float bv = 0.f;
    if (BIAS) bv = bias[col];
    #pragma unroll
    for (int i = 0; i < 4; ++i) {
      int row0 = bm + wm * 64 + i * 16 + (lane >> 4) * 4;
      #pragma unroll
      for (int r = 0; r < 4; ++r)
        Cb[(size_t)(row0 + r) * ldc + col] = f2b(acc[i][j][r] + bv);
    }
  }
}

// ---------------- attention: one block per (b, head), S=64, DK=64 ----------------
// Q/O: row stride qld, head cols h*64.. ; K,V: row stride kvld (V ptr pre-offset).
// O aliases Q (all Q reads precede the single __syncthreads; blocks own disjoint
// (b,h) slices).
template<int CAUSAL>
__global__ __launch_bounds__(256) void attn_kernel(
    u16* Q, const u16* __restrict__ Kb, const u16* __restrict__ Vb,
    const int* __restrict__ mask, int qld, int kvld) {
  __shared__ u16 Ks[64 * 72];
  __shared__ u16 Vt[64 * 72];      // transposed: Vt[d][k]
  __shared__ u16 Ps[4][16 * 72];
  const int bh = blockIdx.x;
  const int b = bh >> 3, h = bh & 7;
  const int h0 = h * 64;
  const int tid = threadIdx.x, lane = tid & 63, w = tid >> 6;
  const size_t qbase = (size_t)b * 64 * qld + h0;
  const size_t kbase = (size_t)b * 64 * kvld + h0;
  const int l15 = lane & 15, l16 = (lane >> 4) * 8;

  { // stage K and V^T
    int r = tid >> 2;
    int c = (tid & 3) * 16;
    const u16* ksrc = Kb + kbase + (size_t)r * kvld + c;
    *(u16x8*)&Ks[r * 72 + c]     = *(const u16x8*)ksrc;
    *(u16x8*)&Ks[r * 72 + c + 8] = *(const u16x8*)(ksrc + 8);
    const u16* vsrc = Vb + kbase + (size_t)r * kvld + c;
    u16x8 t0 = *(const u16x8*)vsrc;
    u16x8 t1 = *(const u16x8*)(vsrc + 8);
    #pragma unroll
    for (int i = 0; i < 8; ++i) {
      Vt[(c + i) * 72 + r]     = t0[i];
      Vt[(c + 8 + i) * 72 + r] = t1[i];
    }
  }
  const int qrow = w * 16 + l15;
  const u16* qp = Q + qbase + (size_t)qrow * qld;
  bf16x8 qf0 = *(const bf16x8*)&qp[l16];
  bf16x8 qf1 = *(const bf16x8*)&qp[32 + l16];
  __syncthreads();

  // scores = Q K^T
  f32x4 sc[4] = {};
  #pragma unroll
  for (int nf = 0; nf < 4; ++nf) {
    bf16x8 k0 = *(const bf16x8*)&Ks[(nf * 16 + l15) * 72 + l16];
    bf16x8 k1 = *(const bf16x8*)&Ks[(nf * 16 + l15) * 72 + 32 + l16];
    sc[nf] = mfma16(qf0, k0, sc[nf]);
    sc[nf] = mfma16(qf1, k1, sc[nf]);
  }
  // mask + scale; lane holds rows q=w*16+(lane>>4)*4+r, cols k=nf*16+(lane&15)
  int mk[4];
  #pragma unroll
  for (int nf = 0; nf < 4; ++nf) mk[nf] = mask[b * 64 + nf * 16 + l15];
  float pv[4][4];
  #pragma unroll
  for (int r = 0; r < 4; ++r) {
    int q = w * 16 + (lane >> 4) * 4 + r;
    #pragma unroll
    for (int nf = 0; nf < 4; ++nf) {
      int k = nf * 16 + l15;
      bool kp = (mk[nf] != 0);
      if (CAUSAL) kp = kp && (k <= q);
      pv[r][nf] = kp ? sc[nf][r] * 0.125f : -1e9f;
    }
  }
  // softmax per row across the 16-lane group
  #pragma unroll
  for (int r = 0; r < 4; ++r) {
    float mx = fmaxf(fmaxf(pv[r][0], pv[r][1]), fmaxf(pv[r][2], pv[r][3]));
    #pragma unroll
    for (int off = 1; off < 16; off <<= 1) mx = fmaxf(mx, __shfl_xor(mx, off));
    float sum = 0.f;
    #pragma unroll
    for (int nf = 0; nf < 4; ++nf) { pv[r][nf] = __expf(pv[r][nf] - mx); sum += pv[r][nf]; }
    #pragma unroll
    for (int off = 1; off < 16; off <<= 1) sum += __shfl_xor(sum, off);
    float inv = 1.0f / sum;
    #pragma unroll
    for (int nf = 0; nf < 4; ++nf) pv[r][nf] *= inv;
  }
  // P -> LDS (per-wave private region)
  #pragma unroll
  for (int r = 0; r < 4; ++r) {
    int q = (lane >> 4) * 4 + r;
    #pragma unroll
    for (int nf = 0; nf < 4; ++nf)
      Ps[w][q * 72 + nf * 16 + l15] = f2b(pv[r][nf]);
  }
  // O = P V
  f32x4 oacc[4] = {};
  #pragma unroll
  for (int kk = 0; kk < 2; ++kk) {
    bf16x8 pa = *(const bf16x8*)&Ps[w][l15 * 72 + kk * 32 + l16];
    #pragma unroll
    for (int df = 0; df < 4; ++df) {
      bf16x8 vf = *(const bf16x8*)&Vt[(df * 16 + l15) * 72 + kk * 32 + l16];
      oacc[df] = mfma16(pa, vf, oacc[df]);
    }
  }
  #pragma unroll
  for (int df = 0; df < 4; ++df) {
    int col = df * 16 + l15;
    #pragma unroll
    for (int r = 0; r < 4; ++r) {
      int t = w * 16 + (lane >> 4) * 4 + r;
      Q[qbase + (size_t)t * qld + col] = f2b(oacc[df][r]);
    }
  }
}

// ---------------- host side ----------------
extern "C" void kernel_launch(void* const* d_in, const int* in_sizes, int n_in,
                              void* d_out, int out_size, void* d_ws, size_t ws_size,
                              hipStream_t stream) {
  const int* src_ids    = (const int*)d_in[0];
  const int* tgt_ids    = (const int*)d_in[1];
  const int* src_mask   = (const int*)d_in[2];
  const int* tgt_mask   = (const int*)d_in[3];
  const float* src_emb  = (const float*)d_in[4];
  const float* tgt_emb  = (const float*)d_in[5];
  const float* enc_wq = (const float*)d_in[6];
  const float* enc_wk = (const float*)d_in[7];
  const float* enc_wv = (const float*)d_in[8];
  const float* enc_wo = (const float*)d_in[9];
  const float* enc_g  = (const float*)d_in[10];
  const float* enc_b  = (const float*)d_in[11];
  const float* fc1w = (const float*)d_in[12];
  const float* fc1b = (const float*)d_in[13];
  const float* fc2w = (const float*)d_in[14];
  const float* fc2b = (const float*)d_in[15];
  const float* mwq = (const float*)d_in[16];
  const float* mwk = (const float*)d_in[17];
  const float* mwv = (const float*)d_in[18];
  const float* mwo = (const float*)d_in[19];
  const float* cwq = (const float*)d_in[20];
  const float* cwo = (const float*)d_in[21];
  const float* dec_g = (const float*)d_in[22];
  const float* dec_b = (const float*)d_in[23];
  const float* dfw = (const float*)d_in[24];
  const float* dfb = (const float*)d_in[25];
  float* outF = (float*)d_out;
  u16* kvenc = (u16*)d_out;   // encoder K/V [T,1024] parked in d_out (64 MB)

  // workspace: pe | W(bf16 weights) | cur | A | BC   = 194.1 MB
  constexpr size_t SZ_PE = (size_t)SLEN * HD * 4;            // 128 KB
  constexpr size_t SZ_W  = (size_t)114 * EW * 2;             // 59.77 MB
  constexpr size_t SZ_B  = (size_t)TTOK * HD * 2;            // 32 MB
  constexpr size_t NEED  = SZ_PE + SZ_W + 4 * SZ_B;
  if (ws_size < NEED) return;

  char* ws = (char*)d_ws;
  float* pe = (float*)ws;
  u16* W    = (u16*)(ws + SZ_PE);
  u16* cur  = (u16*)(ws + SZ_PE + SZ_W);
  u16* Abuf = (u16*)(ws + SZ_PE + SZ_W + SZ_B);
  u16* BC   = (u16*)(ws + SZ_PE + SZ_W + 2 * SZ_B);  // 64 MB region

  dim3 blk(256);
  dim3 gq(TTOK / 128, HD / 128);       // N=512  full-M
  dim3 gkv(TTOK / 128, 1024 / 128);    // N=1024 full-M
  dim3 gf1(16384 / 128, FFD / 128);    // fc1 half-M
  dim3 gf2(16384 / 128, HD / 128);     // fc2 half-M

  pe_kernel<<<128, blk, 0, stream>>>(pe);

  // ---- weight conversion into bf16 layout ----
  // enc layer stride 12E: q@0 kv@E wo@3E fc1@4E fc2@8E ; dec base 72E stride 7E:
  // q@0 kv@E wo@3E cq@4E co@5E fw@6E
  const unsigned int E = EW, S_E = 12 * EW, S_D = 7 * EW;
  u16* WD = W + (size_t)72 * EW;
  wconv_kernel<<<768,  blk, 0, stream>>>(enc_wq, W,            E,     S_E);
  wconv_kernel<<<768,  blk, 0, stream>>>(enc_wk, W + E,        E,     S_E);
  wconv_kernel<<<768,  blk, 0, stream>>>(enc_wv, W + 2 * E,    E,     S_E);
  wconv_kernel<<<768,  blk, 0, stream>>>(enc_wo, W + 3 * E,    E,     S_E);
  wconv_kernel<<<3072, blk, 0, stream>>>(fc1w,   W + 4 * E,    4 * E, S_E);
  wconv_kernel<<<3072, blk, 0, stream>>>(fc2w,   W + 8 * E,    4 * E, S_E);
  wconv_kernel<<<768,  blk, 0, stream>>>(mwq,    WD,           E,     S_D);
  wconv_kernel<<<768,  blk, 0, stream>>>(mwk,    WD + E,       E,     S_D);
  wconv_kernel<<<768,  blk, 0, stream>>>(mwv,    WD + 2 * E,   E,     S_D);
  wconv_kernel<<<768,  blk, 0, stream>>>(mwo,    WD + 3 * E,   E,     S_D);
  wconv_kernel<<<768,  blk, 0, stream>>>(cwq,    WD + 4 * E,   E,     S_D);
  wconv_kernel<<<768,  blk, 0, stream>>>(cwo,    WD + 5 * E,   E,     S_D);
  wconv_kernel<<<768,  blk, 0, stream>>>(dfw,    WD + 6 * E,   E,     S_D);

  // ---------------- encoder ----------------
  embed_kernel<<<8192, blk, 0, stream>>>(src_ids, src_emb, pe, cur);
  for (int l = 0; l < 6; ++l) {
    const u16* Wl = W + (size_t)l * S_E;
    const float* g  = enc_g + (size_t)l * HD;
    const float* bb = enc_b + (size_t)l * HD;
    const float* b1 = fc1b + (size_t)l * FFD;
    const float* b2 = fc2b + (size_t)l * HD;

    gemm_nt<0><<<gq,  blk, 0, stream>>>(cur, Wl,     nullptr, Abuf, TTOK, HD,   HD, HD, HD);
    gemm_nt<0><<<gkv, blk, 0, stream>>>(cur, Wl + E, nullptr, BC,   TTOK, 1024, HD, HD, 1024);
    attn_kernel<0><<<4096, blk, 0, stream>>>(Abuf, BC, BC + HD, src_mask, HD, 1024);
    if (l == 5)  // park encoder K/V for decoder cross-attn (d_out is free scratch)
      hipMemcpyAsync(kvenc, BC, (size_t)TTOK * 1024 * 2, hipMemcpyDeviceToDevice, stream);
    gemm_nt<0><<<gq, blk, 0, stream>>>(Abuf, Wl + 3 * E, nullptr, BC, TTOK, HD, HD, HD, HD);
    ln_kernel<0><<<8192, blk, 0, stream>>>(cur, BC, g, bb, cur, nullptr);
    for (int c = 0; c < 2; ++c) {   // FFN in 2 half-M chunks through BC (64 MB)
      const u16* ac = cur + (size_t)c * 16384 * HD;
      u16* zc = Abuf + (size_t)c * 16384 * HD;
      gemm_nt<1><<<gf1, blk, 0, stream>>>(ac, Wl + 4 * E, b1, BC, 16384, FFD, HD, HD, FFD);
      gemm_nt<1><<<gf2, blk, 0, stream>>>(BC, Wl + 8 * E, b2, zc, 16384, HD, FFD, FFD, HD);
    }
    ln_kernel<0><<<8192, blk, 0, stream>>>(cur, Abuf, g, bb, cur, nullptr);
  }

  // ---------------- decoder ----------------
  embed_kernel<<<8192, blk, 0, stream>>>(tgt_ids, tgt_emb, pe, cur);
  for (int l = 0; l < 6; ++l) {
    const u16* Wl = WD + (size_t)l * S_D;
    const float* g  = dec_g + (size_t)l * HD;
    const float* bb = dec_b + (size_t)l * HD;
    const float* fb = dfb + (size_t)l * HD;

    gemm_nt<0><<<gq,  blk, 0, stream>>>(cur, Wl,     nullptr, Abuf, TTOK, HD,   HD, HD, HD);
    gemm_nt<0><<<gkv, blk, 0, stream>>>(cur, Wl + E, nullptr, BC,   TTOK, 1024, HD, HD, 1024);
    attn_kernel<1><<<4096, blk, 0, stream>>>(Abuf, BC, BC + HD, tgt_mask, HD, 1024);
    gemm_nt<0><<<gq, blk, 0, stream>>>(Abuf, Wl + 3 * E, nullptr, BC, TTOK, HD, HD, HD, HD);
    ln_kernel<0><<<8192, blk, 0, stream>>>(cur, BC, g, bb, cur, nullptr);

    gemm_nt<0><<<gq, blk, 0, stream>>>(cur, Wl + 4 * E, nullptr, Abuf, TTOK, HD, HD, HD, HD);
    attn_kernel<1><<<4096, blk, 0, stream>>>(Abuf, kvenc, kvenc + HD, tgt_mask, HD, 1024);
    gemm_nt<0><<<gq, blk, 0, stream>>>(Abuf, Wl + 5 * E, nullptr, BC, TTOK, HD, HD, HD, HD);
    ln_kernel<0><<<8192, blk, 0, stream>>>(cur, BC, g, bb, cur, nullptr);

    gemm_nt<1><<<gq, blk, 0, stream>>>(cur, Wl + 6 * E, fb, BC, TTOK, HD, HD, HD, HD);
    if (l == 5)
      ln_kernel<1><<<8192, blk, 0, stream>>>(cur, BC, g, bb, nullptr, outF);
    else
      ln_kernel<0><<<8192, blk, 0, stream>>>(cur, BC, g, bb, cur, nullptr);
  }
  (void)in_sizes; (void)n_in; (void)out_size;
}

// Round 5
// 4107.293 us; speedup vs baseline: 1.4612x; 1.1292x over previous
//
#include <hip/hip_runtime.h>

typedef unsigned short u16;
typedef u16 u16x8 __attribute__((ext_vector_type(8)));
typedef __bf16 bf16x8 __attribute__((ext_vector_type(8)));
typedef float f32x4 __attribute__((ext_vector_type(4)));

#define TTOK 32768
#define HD 512
#define FFD 2048
#define SLEN 64
#define EW 262144            // 512*512 elems

__device__ __forceinline__ float b2f(u16 u) {
  union { float f; unsigned int i; } v; v.i = ((unsigned int)u) << 16; return v.f;
}
__device__ __forceinline__ u16 f2b(float f) {
  union { float f; unsigned int i; } v; v.f = f;
  unsigned int i = v.i;
  return (u16)((i + 0x7FFFu + ((i >> 16) & 1u)) >> 16);  // RNE
}

__device__ __forceinline__ void gload16(const u16* g, u16* l) {
  __builtin_amdgcn_global_load_lds((const __attribute__((address_space(1))) void*)g,
                                   (__attribute__((address_space(3))) void*)l,
                                   16, 0, 0);
}

__device__ __forceinline__ f32x4 mfma16(bf16x8 a, bf16x8 b, f32x4 c) {
  return __builtin_amdgcn_mfma_f32_16x16x32_bf16(a, b, c, 0, 0, 0);
}

// ---------------- positional encoding table [S,H] f32 ----------------
__global__ __launch_bounds__(256) void pe_kernel(float* __restrict__ pe) {
  int idx = blockIdx.x * 256 + threadIdx.x;
  int s = idx >> 9, h = idx & 511;
  float e2i = (float)(h & ~1);
  float ang = (float)s * powf(10000.0f, -e2i * (1.0f / 512.0f));
  pe[idx] = (h & 1) ? cosf(ang) : sinf(ang);
}

// ------------- weight convert f32 -> bf16, per-layer strided dest -------------
__global__ __launch_bounds__(256) void wconv_kernel(
    const float* __restrict__ src, u16* __restrict__ dst,
    unsigned int npl, unsigned int dstride) {
  size_t i = ((size_t)blockIdx.x * 256 + threadIdx.x) * 8;
  unsigned int l = (unsigned int)(i / npl);
  unsigned int r = (unsigned int)(i - (size_t)l * npl);
  f32x4 a = *(const f32x4*)(src + i), b = *(const f32x4*)(src + i + 4);
  u16x8 o;
  #pragma unroll
  for (int k = 0; k < 4; ++k) { o[k] = f2b(a[k]); o[4 + k] = f2b(b[k]); }
  *(u16x8*)(dst + (size_t)l * dstride + r) = o;
}

// ---------------- embedding (f32) + PE (f32) -> bf16 ----------------
__global__ __launch_bounds__(256) void embed_kernel(
    const int* __restrict__ ids, const float* __restrict__ emb,
    const float* __restrict__ pe, u16* __restrict__ outB) {
  int chunk = blockIdx.x * 256 + threadIdx.x;
  int t = chunk >> 6;
  int c8 = (chunk & 63) * 8;
  int s = t & (SLEN - 1);
  int id = ids[t];
  const float* e = emb + (size_t)id * HD + c8;
  const float* p = pe + s * HD + c8;
  f32x4 e0 = *(const f32x4*)e, e1 = *(const f32x4*)(e + 4);
  f32x4 p0 = *(const f32x4*)p, p1 = *(const f32x4*)(p + 4);
  u16x8 ob;
  #pragma unroll
  for (int i = 0; i < 4; ++i) {
    ob[i]     = f2b(e0[i] + p0[i]);
    ob[4 + i] = f2b(e1[i] + p1[i]);
  }
  *(u16x8*)(outB + (size_t)t * HD + c8) = ob;
}

// ---------------- save K|V cols (stride 1536) to dense [T,1024] ----------------
__global__ __launch_bounds__(256) void kvsave_kernel(
    const u16* __restrict__ src, u16* __restrict__ dst) {
  int idx = blockIdx.x * 256 + threadIdx.x;      // T*1024/8
  int t = idx >> 7, c = (idx & 127) * 8;
  *(u16x8*)(dst + (size_t)t * 1024 + c) =
      *(const u16x8*)(src + (size_t)t * 1536 + 512 + c);
}

// ---------------- residual + layernorm (bf16 in, f32 params) ----------------
// outB may alias A (in-place): each thread reads its 8 elems before any write.
template<int F32OUT>
__global__ __launch_bounds__(256) void ln_kernel(
    const u16* A, const u16* __restrict__ Z, int ldz,
    const float* __restrict__ g, const float* __restrict__ b,
    u16* outB, float* outF) {
  int row = blockIdx.x * 4 + (threadIdx.x >> 6);
  int lane = threadIdx.x & 63;
  size_t base = (size_t)row * HD + lane * 8;
  size_t zbase = (size_t)row * ldz + lane * 8;
  u16x8 av = *(const u16x8*)(A + base);
  u16x8 zv = *(const u16x8*)(Z + zbase);
  float x[8];
  float s = 0.f;
  #pragma unroll
  for (int i = 0; i < 8; ++i) { x[i] = b2f(av[i]) + b2f(zv[i]); s += x[i]; }
  #pragma unroll
  for (int off = 32; off; off >>= 1) s += __shfl_xor(s, off);
  float m = s * (1.0f / HD);
  float vs = 0.f;
  #pragma unroll
  for (int i = 0; i < 8; ++i) { float d = x[i] - m; vs += d * d; }
  #pragma unroll
  for (int off = 32; off; off >>= 1) vs += __shfl_xor(vs, off);
  float rstd = rsqrtf(vs * (1.0f / HD) + 1e-5f);
  f32x4 g0 = *(const f32x4*)(g + lane * 8), g1 = *(const f32x4*)(g + lane * 8 + 4);
  f32x4 b0 = *(const f32x4*)(b + lane * 8), b1 = *(const f32x4*)(b + lane * 8 + 4);
  float o[8];
  #pragma unroll
  for (int i = 0; i < 4; ++i) {
    o[i]     = (x[i] - m) * rstd * g0[i] + b0[i];
    o[4 + i] = (x[4 + i] - m) * rstd * g1[i] + b1[i];
  }
  if (F32OUT) {
    f32x4 o0, o1;
    #pragma unroll
    for (int i = 0; i < 4; ++i) { o0[i] = o[i]; o1[i] = o[4 + i]; }
    *(f32x4*)(outF + base) = o0;
    *(f32x4*)(outF + base + 4) = o1;
  } else {
    u16x8 ob;
    #pragma unroll
    for (int i = 0; i < 8; ++i) ob[i] = f2b(o[i]);
    *(u16x8*)(outB + base) = ob;
  }
}

// ===================== 256x256 8-phase pipelined bf16 NT GEMM =====================
// C[M,N] = A[M,K] @ Bw[N,K]^T (+bias) (+= existing C if ACC), bf16 out.
// 512 threads = 8 waves (2M x 4N), per-wave C = 128x64. BK=64, processed as two
// 32-wide K-halves. LDS: ring of 4 K-half slots per operand ([128][64]-shaped,
// 16 KB each, XOR-swizzled byte^=((row&7)<<4)); stages run 4 units ahead of reads;
// counted vmcnt(8) twice per K-tile (never 0 in loop); raw s_barrier only.
#define BAR() __builtin_amdgcn_s_barrier()
#define WAIT_LGKM0() asm volatile("s_waitcnt lgkmcnt(0)" ::: "memory")
#define WAIT_VM8()   asm volatile("s_waitcnt vmcnt(8)" ::: "memory")

template<int BIAS, int ACC>
__global__ __launch_bounds__(512, 2) void gemm256(
    const u16* __restrict__ A, const u16* __restrict__ Bw,
    const float* __restrict__ bias, u16* __restrict__ Cb,
    int nbn, int K, int lda, int ldb, int ldc) {
  __shared__ u16 lds[65536];               // A: 4x8192 elems, B: +32768
  const int tid = threadIdx.x;
  const int lane = tid & 63, w = tid >> 6;
  const int wr = w >> 2, wc = w & 3;
  const int l15 = lane & 15, lq = lane >> 4;

  // XCD-bijective block swizzle (all grids are multiples of 8)
  const int cpx = gridDim.x >> 3;
  const int L = (blockIdx.x & 7) * cpx + (blockIdx.x >> 3);
  const int bm = (L / nbn) * 256, bn = (L % nbn) * 256;

  // ---- staging source precompute (pre-swizzled global addresses) ----
  // lane writes LDS physical p = w*1024 + i*8192 + lane*16 (bytes, in-slot);
  // it must fetch the element whose logical byte is lb = p ^ (((p>>7)&7)<<4).
  const u16 *pa0, *pa1, *pb0, *pb1;
  {
    int p0 = w * 1024 + lane * 16;
    int p1 = p0 + 8192;
    int lb0 = p0 ^ (((p0 >> 7) & 7) << 4);
    int lb1 = p1 ^ (((p1 >> 7) & 7) << 4);
    int r0 = (lb0 >> 7) + (((lb0 >> 6) & 1) << 7);   // [128][64]-fold: row' + colgrp*128
    int r1 = (lb1 >> 7) + (((lb1 >> 6) & 1) << 7);
    int c0 = (lb0 & 63) >> 1;                         // elems within 32-wide K-half
    int c1 = (lb1 & 63) >> 1;
    pa0 = A  + (size_t)(bm + r0) * lda + c0;
    pa1 = A  + (size_t)(bm + r1) * lda + c1;
    pb0 = Bw + (size_t)(bn + r0) * ldb + c0;
    pb1 = Bw + (size_t)(bn + r1) * ldb + c1;
  }
  const int dst = w * 512;   // elems, wave-uniform LDS dest base (in-slot)

  // ---- fragment ds_read element offsets (swizzled, within slot) ----
  int offA[8], offB[4];
  #pragma unroll
  for (int mf = 0; mf < 8; ++mf) {
    int rowp = mf * 16 + l15;                        // 0..127
    offA[mf] = ((rowp * 128 + wr * 64 + lq * 16) ^ ((l15 & 7) << 4)) >> 1;
  }
  #pragma unroll
  for (int j = 0; j < 4; ++j) {
    int rB = wc * 64 + j * 16 + l15;                 // 0..255
    int rowp = rB & 127, cg = rB >> 7;
    offB[j] = ((rowp * 128 + cg * 64 + lq * 16) ^ ((l15 & 7) << 4)) >> 1;
  }

  const int NK2 = K >> 5;    // # of 32-wide K-halves
  const int NT  = K >> 6;    // # of 64-wide K-tiles

#define STAGEA(kh, slot) { \
    gload16(pa0 + (kh) * 32, &lds[(slot) * 8192 + dst]); \
    gload16(pa1 + (kh) * 32, &lds[(slot) * 8192 + dst + 4096]); }
#define STAGEB(kh, slot) { \
    gload16(pb0 + (kh) * 32, &lds[32768 + (slot) * 8192 + dst]); \
    gload16(pb1 + (kh) * 32, &lds[32768 + (slot) * 8192 + dst + 4096]); }
#define LDA4(slot, mh) { \
    _Pragma("unroll") for (int i = 0; i < 4; ++i) \
      af[i] = *(const bf16x8*)&lds[(slot) * 8192 + offA[(mh) * 4 + i]]; }
#define LDB4(slot) { \
    _Pragma("unroll") for (int j = 0; j < 4; ++j) \
      bf[j] = *(const bf16x8*)&lds[32768 + (slot) * 8192 + offB[j]]; }
#define MFMA16(mh) { \
    __builtin_amdgcn_s_setprio(1); \
    _Pragma("unroll") for (int i = 0; i < 4; ++i) \
      _Pragma("unroll") for (int j = 0; j < 4; ++j) \
        acc[(mh) * 4 + i][j] = mfma16(af[i], bf[j], acc[(mh) * 4 + i][j]); \
    __builtin_amdgcn_s_setprio(0); }

  f32x4 acc[8][4] = {};
  bf16x8 af[4], bf[4];

  // prologue: stage K-halves 0,1,2 (A+B each); kh0 guaranteed landed by vmcnt(8)
  STAGEA(0, 0); STAGEB(0, 0);
  STAGEA(1, 1); STAGEB(1, 1);
  STAGEA(2, 2); STAGEB(2, 2);
  WAIT_VM8();
  BAR();

  for (int t = 0; t < NT; ++t) {
    const int s0 = (2 * t) & 3, s1 = (2 * t + 1) & 3;
    int kh3 = 2 * t + 3; if (kh3 > NK2 - 1) kh3 = NK2 - 1;
    int kh4 = 2 * t + 4; if (kh4 > NK2 - 1) kh4 = NK2 - 1;
    const int w3 = (2 * t + 3) & 3, w4 = (2 * t + 4) & 3;

    // ---- P1: kk=0, mh=0 ----
    LDB4(s0); LDA4(s0, 0);
    STAGEA(kh3, w3);
    BAR(); WAIT_LGKM0();
    MFMA16(0);
    BAR();
    // ---- P2: kk=0, mh=1 ----
    LDA4(s0, 1);
    STAGEB(kh3, w3);
    BAR(); WAIT_LGKM0();
    MFMA16(1);
    WAIT_VM8();               // guards next phases' reads of K-half 2t+1
    BAR();
    // ---- P3: kk=1, mh=0 ----
    LDB4(s1); LDA4(s1, 0);
    STAGEA(kh4, w4);
    BAR(); WAIT_LGKM0();
    MFMA16(0);
    BAR();
    // ---- P4: kk=1, mh=1 ----
    LDA4(s1, 1);
    STAGEB(kh4, w4);
    BAR(); WAIT_LGKM0();
    MFMA16(1);
    WAIT_VM8();               // guards next tile's reads of K-half 2t+2
    BAR();
  }
  asm volatile("s_waitcnt vmcnt(0)" ::: "memory");   // drain tail stages

  // ---- epilogue ----
  #pragma unroll
  for (int j = 0; j < 4; ++j) {
    int col = bn + wc * 64 + j * 16 + l15;
    float bv = 0.f;
    if (BIAS) bv = bias[col];
    #pragma unroll
    for (int mf = 0; mf < 8; ++mf) {
      int row0 = bm + wr * 128 + mf * 16 + lq * 4;
      #pragma unroll
      for (int r = 0; r < 4; ++r) {
        size_t off = (size_t)(row0 + r) * ldc + col;
        float v = acc[mf][j][r] + bv;
        if (ACC) v += b2f(Cb[off]);
        Cb[off] = f2b(v);
      }
    }
  }
#undef STAGEA
#undef STAGEB
#undef LDA4
#undef LDB4
#undef MFMA16
}

// ---------------- attention: one block per (b, head), S=64, DK=64 ----------------
// Q/O: row stride qld, head cols h*64.. ; K,V: row stride kvld (V ptr pre-offset).
// O aliases Q (all Q reads precede the single __syncthreads).
template<int CAUSAL>
__global__ __launch_bounds__(256) void attn_kernel(
    u16* Q, const u16* __restrict__ Kb, const u16* __restrict__ Vb,
    const int* __restrict__ mask, int qld, int kvld) {
  __shared__ u16 Ks[64 * 72];
  __shared__ u16 Vt[64 * 72];
  __shared__ u16 Ps[4][16 * 72];
  const int bh = blockIdx.x;
  const int b = bh >> 3, h = bh & 7;
  const int h0 = h * 64;
  const int tid = threadIdx.x, lane = tid & 63, w = tid >> 6;
  const size_t qbase = (size_t)b * 64 * qld + h0;
  const size_t kbase = (size_t)b * 64 * kvld + h0;
  const int l15 = lane & 15, l16 = (lane >> 4) * 8;

  {
    int r = tid >> 2;
    int c = (tid & 3) * 16;
    const u16* ksrc = Kb + kbase + (size_t)r * kvld + c;
    *(u16x8*)&Ks[r * 72 + c]     = *(const u16x8*)ksrc;
    *(u16x8*)&Ks[r * 72 + c + 8] = *(const u16x8*)(ksrc + 8);
    const u16* vsrc = Vb + kbase + (size_t)r * kvld + c;
    u16x8 t0 = *(const u16x8*)vsrc;
    u16x8 t1 = *(const u16x8*)(vsrc + 8);
    #pragma unroll
    for (int i = 0; i < 8; ++i) {
      Vt[(c + i) * 72 + r]     = t0[i];
      Vt[(c + 8 + i) * 72 + r] = t1[i];
    }
  }
  const int qrow = w * 16 + l15;
  const u16* qp = Q + qbase + (size_t)qrow * qld;
  bf16x8 qf0 = *(const bf16x8*)&qp[l16];
  bf16x8 qf1 = *(const bf16x8*)&qp[32 + l16];
  __syncthreads();

  f32x4 sc[4] = {};
  #pragma unroll
  for (int nf = 0; nf < 4; ++nf) {
    bf16x8 k0 = *(const bf16x8*)&Ks[(nf * 16 + l15) * 72 + l16];
    bf16x8 k1 = *(const bf16x8*)&Ks[(nf * 16 + l15) * 72 + 32 + l16];
    sc[nf] = mfma16(qf0, k0, sc[nf]);
    sc[nf] = mfma16(qf1, k1, sc[nf]);
  }
  int mk[4];
  #pragma unroll
  for (int nf = 0; nf < 4; ++nf) mk[nf] = mask[b * 64 + nf * 16 + l15];
  float pv[4][4];
  #pragma unroll
  for (int r = 0; r < 4; ++r) {
    int q = w * 16 + (lane >> 4) * 4 + r;
    #pragma unroll
    for (int nf = 0; nf < 4; ++nf) {
      int k = nf * 16 + l15;
      bool kp = (mk[nf] != 0);
      if (CAUSAL) kp = kp && (k <= q);
      pv[r][nf] = kp ? sc[nf][r] * 0.125f : -1e9f;
    }
  }
  #pragma unroll
  for (int r = 0; r < 4; ++r) {
    float mx = fmaxf(fmaxf(pv[r][0], pv[r][1]), fmaxf(pv[r][2], pv[r][3]));
    #pragma unroll
    for (int off = 1; off < 16; off <<= 1) mx = fmaxf(mx, __shfl_xor(mx, off));
    float sum = 0.f;
    #pragma unroll
    for (int nf = 0; nf < 4; ++nf) { pv[r][nf] = __expf(pv[r][nf] - mx); sum += pv[r][nf]; }
    #pragma unroll
    for (int off = 1; off < 16; off <<= 1) sum += __shfl_xor(sum, off);
    float inv = 1.0f / sum;
    #pragma unroll
    for (int nf = 0; nf < 4; ++nf) pv[r][nf] *= inv;
  }
  #pragma unroll
  for (int r = 0; r < 4; ++r) {
    int q = (lane >> 4) * 4 + r;
    #pragma unroll
    for (int nf = 0; nf < 4; ++nf)
      Ps[w][q * 72 + nf * 16 + l15] = f2b(pv[r][nf]);
  }
  f32x4 oacc[4] = {};
  #pragma unroll
  for (int kk = 0; kk < 2; ++kk) {
    bf16x8 pa = *(const bf16x8*)&Ps[w][l15 * 72 + kk * 32 + l16];
    #pragma unroll
    for (int df = 0; df < 4; ++df) {
      bf16x8 vf = *(const bf16x8*)&Vt[(df * 16 + l15) * 72 + kk * 32 + l16];
      oacc[df] = mfma16(pa, vf, oacc[df]);
    }
  }
  #pragma unroll
  for (int df = 0; df < 4; ++df) {
    int col = df * 16 + l15;
    #pragma unroll
    for (int r = 0; r < 4; ++r) {
      int t = w * 16 + (lane >> 4) * 4 + r;
      Q[qbase + (size_t)t * qld + col] = f2b(oacc[df][r]);
    }
  }
}

// ---------------- host side ----------------
extern "C" void kernel_launch(void* const* d_in, const int* in_sizes, int n_in,
                              void* d_out, int out_size, void* d_ws, size_t ws_size,
                              hipStream_t stream) {
  const int* src_ids    = (const int*)d_in[0];
  const int* tgt_ids    = (const int*)d_in[1];
  const int* src_mask   = (const int*)d_in[2];
  const int* tgt_mask   = (const int*)d_in[3];
  const float* src_emb  = (const float*)d_in[4];
  const float* tgt_emb  = (const float*)d_in[5];
  const float* enc_wq = (const float*)d_in[6];
  const float* enc_wk = (const float*)d_in[7];
  const float* enc_wv = (const float*)d_in[8];
  const float* enc_wo = (const float*)d_in[9];
  const float* enc_g  = (const float*)d_in[10];
  const float* enc_b  = (const float*)d_in[11];
  const float* fc1w = (const float*)d_in[12];
  const float* fc1b = (const float*)d_in[13];
  const float* fc2w = (const float*)d_in[14];
  const float* fc2b = (const float*)d_in[15];
  const float* mwq = (const float*)d_in[16];
  const float* mwk = (const float*)d_in[17];
  const float* mwv = (const float*)d_in[18];
  const float* mwo = (const float*)d_in[19];
  const float* cwq = (const float*)d_in[20];
  const float* cwo = (const float*)d_in[21];
  const float* dec_g = (const float*)d_in[22];
  const float* dec_b = (const float*)d_in[23];
  const float* dfw = (const float*)d_in[24];
  const float* dfb = (const float*)d_in[25];
  float* outF = (float*)d_out;
  u16* kvenc = (u16*)d_out;   // encoder [K|V] dense [T,1024] parked in d_out (64 MB)

  // workspace: pe | W(bf16 weights) | cur | QKV(96MB, recycled as inter+z2) = 187.9 MB
  constexpr size_t SZ_PE  = (size_t)SLEN * HD * 4;
  constexpr size_t SZ_W   = (size_t)114 * EW * 2;
  constexpr size_t SZ_CUR = (size_t)TTOK * HD * 2;            // 32 MB
  constexpr size_t SZ_QKV = (size_t)TTOK * 1536 * 2;          // 96 MB
  constexpr size_t NEED   = SZ_PE + SZ_W + SZ_CUR + SZ_QKV;
  if (ws_size < NEED) return;

  char* ws = (char*)d_ws;
  float* pe = (float*)ws;
  u16* W    = (u16*)(ws + SZ_PE);
  u16* cur  = (u16*)(ws + SZ_PE + SZ_W);
  u16* qkv  = (u16*)(ws + SZ_PE + SZ_W + SZ_CUR);
  u16* z2   = qkv + (size_t)TTOK * 1024;    // fc2 out [T,512] in top third of QKV

  dim3 blk(256), blk5(512);
  const unsigned int E = EW, S_E = 12 * EW, S_D = 7 * EW;
  u16* WD = W + (size_t)72 * EW;

  pe_kernel<<<128, blk, 0, stream>>>(pe);

  // weight conversion (enc: qkv stacked @0, wo@3E, fc1@4E, fc2@8E; dec: qkv@0,
  // wo@3E, cq@4E, co@5E, fw@6E)
  wconv_kernel<<<768,  blk, 0, stream>>>(enc_wq, W,          E,     S_E);
  wconv_kernel<<<768,  blk, 0, stream>>>(enc_wk, W + E,      E,     S_E);
  wconv_kernel<<<768,  blk, 0, stream>>>(enc_wv, W + 2 * E,  E,     S_E);
  wconv_kernel<<<768,  blk, 0, stream>>>(enc_wo, W + 3 * E,  E,     S_E);
  wconv_kernel<<<3072, blk, 0, stream>>>(fc1w,   W + 4 * E,  4 * E, S_E);
  wconv_kernel<<<3072, blk, 0, stream>>>(fc2w,   W + 8 * E,  4 * E, S_E);
  wconv_kernel<<<768,  blk, 0, stream>>>(mwq,    WD,         E,     S_D);
  wconv_kernel<<<768,  blk, 0, stream>>>(mwk,    WD + E,     E,     S_D);
  wconv_kernel<<<768,  blk, 0, stream>>>(mwv,    WD + 2 * E, E,     S_D);
  wconv_kernel<<<768,  blk, 0, stream>>>(mwo,    WD + 3 * E, E,     S_D);
  wconv_kernel<<<768,  blk, 0, stream>>>(cwq,    WD + 4 * E, E,     S_D);
  wconv_kernel<<<768,  blk, 0, stream>>>(cwo,    WD + 5 * E, E,     S_D);
  wconv_kernel<<<768,  blk, 0, stream>>>(dfw,    WD + 6 * E, E,     S_D);

  // ---------------- encoder ----------------
  embed_kernel<<<8192, blk, 0, stream>>>(src_ids, src_emb, pe, cur);
  for (int l = 0; l < 6; ++l) {
    const u16* Wl = W + (size_t)l * S_E;
    const float* g  = enc_g + (size_t)l * HD;
    const float* bb = enc_b + (size_t)l * HD;
    const float* b1 = fc1b + (size_t)l * FFD;
    const float* b2 = fc2b + (size_t)l * HD;

    // fused QKV projection: [T,1536]
    gemm256<0,0><<<768, blk5, 0, stream>>>(cur, Wl, nullptr, qkv, 6, 512, 512, 512, 1536);
    attn_kernel<0><<<4096, blk, 0, stream>>>(qkv, qkv + 512, qkv + 1024, src_mask, 1536, 1536);
    if (l == 5)
      kvsave_kernel<<<16384, blk, 0, stream>>>(qkv, kvenc);
    // wo: A = O (Q-cols, stride 1536) -> Z into V-cols (stride 1536)
    gemm256<0,0><<<256, blk5, 0, stream>>>(qkv, Wl + 3 * E, nullptr, qkv + 1024, 2, 512, 1536, 512, 1536);
    ln_kernel<0><<<8192, blk, 0, stream>>>(cur, qkv + 1024, 1536, g, bb, cur, nullptr);
    // FFN: fc1 split by N (inter [T,1024] dense at qkv base), fc2 split by K (acc)
    gemm256<1,0><<<512, blk5, 0, stream>>>(cur, Wl + 4 * E, b1,        qkv, 4, 512, 512, 512, 1024);
    gemm256<1,0><<<256, blk5, 0, stream>>>(qkv, Wl + 8 * E, b2,        z2,  2, 1024, 1024, 2048, 512);
    gemm256<1,0><<<512, blk5, 0, stream>>>(cur, Wl + 6 * E, b1 + 1024, qkv, 4, 512, 512, 512, 1024);
    gemm256<0,1><<<256, blk5, 0, stream>>>(qkv, Wl + 8 * E + 1024, nullptr, z2, 2, 1024, 1024, 2048, 512);
    ln_kernel<0><<<8192, blk, 0, stream>>>(cur, z2, 512, g, bb, cur, nullptr);
  }

  // ---------------- decoder ----------------
  embed_kernel<<<8192, blk, 0, stream>>>(tgt_ids, tgt_emb, pe, cur);
  for (int l = 0; l < 6; ++l) {
    const u16* Wl = WD + (size_t)l * S_D;
    const float* g  = dec_g + (size_t)l * HD;
    const float* bb = dec_b + (size_t)l * HD;
    const float* fb = dfb + (size_t)l * HD;

    gemm256<0,0><<<768, blk5, 0, stream>>>(cur, Wl, nullptr, qkv, 6, 512, 512, 512, 1536);
    attn_kernel<1><<<4096, blk, 0, stream>>>(qkv, qkv + 512, qkv + 1024, tgt_mask, 1536, 1536);
    gemm256<0,0><<<256, blk5, 0, stream>>>(qkv, Wl + 3 * E, nullptr, qkv + 1024, 2, 512, 1536, 512, 1536);
    ln_kernel<0><<<8192, blk, 0, stream>>>(cur, qkv + 1024, 1536, g, bb, cur, nullptr);

    // cross-attn: Qc into Q-cols; K/V from parked encoder buffer (stride 1024)
    gemm256<0,0><<<256, blk5, 0, stream>>>(cur, Wl + 4 * E, nullptr, qkv, 2, 512, 512, 512, 1536);
    attn_kernel<1><<<4096, blk, 0, stream>>>(qkv, kvenc, kvenc + 512, tgt_mask, 1536, 1024);
    gemm256<0,0><<<256, blk5, 0, stream>>>(qkv, Wl + 5 * E, nullptr, qkv + 1024, 2, 512, 1536, 512, 1536);
    ln_kernel<0><<<8192, blk, 0, stream>>>(cur, qkv + 1024, 1536, g, bb, cur, nullptr);

    gemm256<1,0><<<256, blk5, 0, stream>>>(cur, Wl + 6 * E, fb, qkv, 2, 512, 512, 512, 512);
    if (l == 5)
      ln_kernel<1><<<8192, blk, 0, stream>>>(cur, qkv, 512, g, bb, nullptr, outF);
    else
      ln_kernel<0><<<8192, blk, 0, stream>>>(cur, qkv, 512, g, bb, cur, nullptr);
  }
  (void)in_sizes; (void)n_in; (void)out_size;
}

// Round 6
// 3579.239 us; speedup vs baseline: 1.6767x; 1.1475x over previous
//
#include <hip/hip_runtime.h>

typedef unsigned short u16;
typedef u16 u16x8 __attribute__((ext_vector_type(8)));
typedef __bf16 bf16x8 __attribute__((ext_vector_type(8)));
typedef float f32x4 __attribute__((ext_vector_type(4)));

#define TTOK 32768
#define HD 512
#define FFD 2048
#define SLEN 64
#define EW 262144            // 512*512 elems

__device__ __forceinline__ float b2f(u16 u) {
  union { float f; unsigned int i; } v; v.i = ((unsigned int)u) << 16; return v.f;
}
__device__ __forceinline__ u16 f2b(float f) {
  union { float f; unsigned int i; } v; v.f = f;
  unsigned int i = v.i;
  return (u16)((i + 0x7FFFu + ((i >> 16) & 1u)) >> 16);  // RNE
}

__device__ __forceinline__ void gload16(const u16* g, u16* l) {
  __builtin_amdgcn_global_load_lds((const __attribute__((address_space(1))) void*)g,
                                   (__attribute__((address_space(3))) void*)l,
                                   16, 0, 0);
}

__device__ __forceinline__ f32x4 mfma16(bf16x8 a, bf16x8 b, f32x4 c) {
  return __builtin_amdgcn_mfma_f32_16x16x32_bf16(a, b, c, 0, 0, 0);
}

// ---------------- positional encoding table [S,H] f32 ----------------
__global__ __launch_bounds__(256) void pe_kernel(float* __restrict__ pe) {
  int idx = blockIdx.x * 256 + threadIdx.x;
  int s = idx >> 9, h = idx & 511;
  float e2i = (float)(h & ~1);
  float ang = (float)s * powf(10000.0f, -e2i * (1.0f / 512.0f));
  pe[idx] = (h & 1) ? cosf(ang) : sinf(ang);
}

// ------------- weight convert f32 -> bf16, per-layer strided dest -------------
__global__ __launch_bounds__(256) void wconv_kernel(
    const float* __restrict__ src, u16* __restrict__ dst,
    unsigned int npl, unsigned int dstride) {
  size_t i = ((size_t)blockIdx.x * 256 + threadIdx.x) * 8;
  unsigned int l = (unsigned int)(i / npl);
  unsigned int r = (unsigned int)(i - (size_t)l * npl);
  f32x4 a = *(const f32x4*)(src + i), b = *(const f32x4*)(src + i + 4);
  u16x8 o;
  #pragma unroll
  for (int k = 0; k < 4; ++k) { o[k] = f2b(a[k]); o[4 + k] = f2b(b[k]); }
  *(u16x8*)(dst + (size_t)l * dstride + r) = o;
}

// ---------------- embedding (f32) + PE (f32) -> bf16 ----------------
__global__ __launch_bounds__(256) void embed_kernel(
    const int* __restrict__ ids, const float* __restrict__ emb,
    const float* __restrict__ pe, u16* __restrict__ outB) {
  int chunk = blockIdx.x * 256 + threadIdx.x;
  int t = chunk >> 6;
  int c8 = (chunk & 63) * 8;
  int s = t & (SLEN - 1);
  int id = ids[t];
  const float* e = emb + (size_t)id * HD + c8;
  const float* p = pe + s * HD + c8;
  f32x4 e0 = *(const f32x4*)e, e1 = *(const f32x4*)(e + 4);
  f32x4 p0 = *(const f32x4*)p, p1 = *(const f32x4*)(p + 4);
  u16x8 ob;
  #pragma unroll
  for (int i = 0; i < 4; ++i) {
    ob[i]     = f2b(e0[i] + p0[i]);
    ob[4 + i] = f2b(e1[i] + p1[i]);
  }
  *(u16x8*)(outB + (size_t)t * HD + c8) = ob;
}

// ---------------- save K|V cols (stride 1536) to dense [T,1024] ----------------
__global__ __launch_bounds__(256) void kvsave_kernel(
    const u16* __restrict__ src, u16* __restrict__ dst) {
  int idx = blockIdx.x * 256 + threadIdx.x;      // T*1024/8
  int t = idx >> 7, c = (idx & 127) * 8;
  *(u16x8*)(dst + (size_t)t * 1024 + c) =
      *(const u16x8*)(src + (size_t)t * 1536 + 512 + c);
}

// ---------------- residual + layernorm (bf16 in, f32 params) ----------------
// outB may alias A (in-place): each thread reads its 8 elems before any write.
template<int F32OUT>
__global__ __launch_bounds__(256) void ln_kernel(
    const u16* A, const u16* __restrict__ Z, int ldz,
    const float* __restrict__ g, const float* __restrict__ b,
    u16* outB, float* outF) {
  int row = blockIdx.x * 4 + (threadIdx.x >> 6);
  int lane = threadIdx.x & 63;
  size_t base = (size_t)row * HD + lane * 8;
  size_t zbase = (size_t)row * ldz + lane * 8;
  u16x8 av = *(const u16x8*)(A + base);
  u16x8 zv = *(const u16x8*)(Z + zbase);
  float x[8];
  float s = 0.f;
  #pragma unroll
  for (int i = 0; i < 8; ++i) { x[i] = b2f(av[i]) + b2f(zv[i]); s += x[i]; }
  #pragma unroll
  for (int off = 32; off; off >>= 1) s += __shfl_xor(s, off);
  float m = s * (1.0f / HD);
  float vs = 0.f;
  #pragma unroll
  for (int i = 0; i < 8; ++i) { float d = x[i] - m; vs += d * d; }
  #pragma unroll
  for (int off = 32; off; off >>= 1) vs += __shfl_xor(vs, off);
  float rstd = rsqrtf(vs * (1.0f / HD) + 1e-5f);
  f32x4 g0 = *(const f32x4*)(g + lane * 8), g1 = *(const f32x4*)(g + lane * 8 + 4);
  f32x4 b0 = *(const f32x4*)(b + lane * 8), b1 = *(const f32x4*)(b + lane * 8 + 4);
  float o[8];
  #pragma unroll
  for (int i = 0; i < 4; ++i) {
    o[i]     = (x[i] - m) * rstd * g0[i] + b0[i];
    o[4 + i] = (x[4 + i] - m) * rstd * g1[i] + b1[i];
  }
  if (F32OUT) {
    f32x4 o0, o1;
    #pragma unroll
    for (int i = 0; i < 4; ++i) { o0[i] = o[i]; o1[i] = o[4 + i]; }
    *(f32x4*)(outF + base) = o0;
    *(f32x4*)(outF + base + 4) = o1;
  } else {
    u16x8 ob;
    #pragma unroll
    for (int i = 0; i < 8; ++i) ob[i] = f2b(o[i]);
    *(u16x8*)(outB + base) = ob;
  }
}

// ===================== 256x256 8-phase pipelined bf16 NT GEMM =====================
// C[M,N] = A[M,K] @ Bw[N,K]^T (+bias) (+= existing C if ACC), bf16 out.
// 512 threads = 8 waves (2M x 4N), per-wave C = 128x64. BK=64, two 32-wide
// K-halves. LDS ring of 4 K-half slots/operand, XOR-swizzled; counted vmcnt(8);
// raw s_barrier only. Epilogue: f32 LDS-staged (2 halves), vectorized u16x8 C
// writes (single final rounding incl. bias/ACC).
#define BAR() __builtin_amdgcn_s_barrier()
#define WAIT_LGKM0() asm volatile("s_waitcnt lgkmcnt(0)" ::: "memory")
#define WAIT_VM8()   asm volatile("s_waitcnt vmcnt(8)" ::: "memory")

template<int BIAS, int ACC>
__global__ __launch_bounds__(512, 2) void gemm256(
    const u16* __restrict__ A, const u16* __restrict__ Bw,
    const float* __restrict__ bias, u16* __restrict__ Cb,
    int nbn, int K, int lda, int ldb, int ldc) {
  __shared__ u16 lds[65536];               // 128 KB
  const int tid = threadIdx.x;
  const int lane = tid & 63, w = tid >> 6;
  const int wr = w >> 2, wc = w & 3;
  const int l15 = lane & 15, lq = lane >> 4;

  // XCD-bijective block swizzle (all grids are multiples of 8)
  const int cpx = gridDim.x >> 3;
  const int L = (blockIdx.x & 7) * cpx + (blockIdx.x >> 3);
  const int bm = (L / nbn) * 256, bn = (L % nbn) * 256;

  // ---- staging source precompute (pre-swizzled global addresses) ----
  const u16 *pa0, *pa1, *pb0, *pb1;
  {
    int p0 = w * 1024 + lane * 16;
    int p1 = p0 + 8192;
    int lb0 = p0 ^ (((p0 >> 7) & 7) << 4);
    int lb1 = p1 ^ (((p1 >> 7) & 7) << 4);
    int r0 = (lb0 >> 7) + (((lb0 >> 6) & 1) << 7);
    int r1 = (lb1 >> 7) + (((lb1 >> 6) & 1) << 7);
    int c0 = (lb0 & 63) >> 1;
    int c1 = (lb1 & 63) >> 1;
    pa0 = A  + (size_t)(bm + r0) * lda + c0;
    pa1 = A  + (size_t)(bm + r1) * lda + c1;
    pb0 = Bw + (size_t)(bn + r0) * ldb + c0;
    pb1 = Bw + (size_t)(bn + r1) * ldb + c1;
  }
  const int dst = w * 512;

  // ---- fragment ds_read element offsets (swizzled, within slot) ----
  int offA[8], offB[4];
  #pragma unroll
  for (int mf = 0; mf < 8; ++mf) {
    int rowp = mf * 16 + l15;
    offA[mf] = ((rowp * 128 + wr * 64 + lq * 16) ^ ((l15 & 7) << 4)) >> 1;
  }
  #pragma unroll
  for (int j = 0; j < 4; ++j) {
    int rB = wc * 64 + j * 16 + l15;
    int rowp = rB & 127, cg = rB >> 7;
    offB[j] = ((rowp * 128 + cg * 64 + lq * 16) ^ ((l15 & 7) << 4)) >> 1;
  }

  const int NK2 = K >> 5;
  const int NT  = K >> 6;

#define STAGEA(kh, slot) { \
    gload16(pa0 + (kh) * 32, &lds[(slot) * 8192 + dst]); \
    gload16(pa1 + (kh) * 32, &lds[(slot) * 8192 + dst + 4096]); }
#define STAGEB(kh, slot) { \
    gload16(pb0 + (kh) * 32, &lds[32768 + (slot) * 8192 + dst]); \
    gload16(pb1 + (kh) * 32, &lds[32768 + (slot) * 8192 + dst + 4096]); }
#define LDA4(slot, mh) { \
    _Pragma("unroll") for (int i = 0; i < 4; ++i) \
      af[i] = *(const bf16x8*)&lds[(slot) * 8192 + offA[(mh) * 4 + i]]; }
#define LDB4(slot) { \
    _Pragma("unroll") for (int j = 0; j < 4; ++j) \
      bf[j] = *(const bf16x8*)&lds[32768 + (slot) * 8192 + offB[j]]; }
#define MFMA16(mh) { \
    __builtin_amdgcn_s_setprio(1); \
    _Pragma("unroll") for (int i = 0; i < 4; ++i) \
      _Pragma("unroll") for (int j = 0; j < 4; ++j) \
        acc[(mh) * 4 + i][j] = mfma16(af[i], bf[j], acc[(mh) * 4 + i][j]); \
    __builtin_amdgcn_s_setprio(0); }

  f32x4 acc[8][4] = {};
  bf16x8 af[4], bf[4];

  // prologue: stage K-halves 0,1,2
  STAGEA(0, 0); STAGEB(0, 0);
  STAGEA(1, 1); STAGEB(1, 1);
  STAGEA(2, 2); STAGEB(2, 2);
  WAIT_VM8();
  BAR();

  for (int t = 0; t < NT; ++t) {
    const int s0 = (2 * t) & 3, s1 = (2 * t + 1) & 3;
    int kh3 = 2 * t + 3; if (kh3 > NK2 - 1) kh3 = NK2 - 1;
    int kh4 = 2 * t + 4; if (kh4 > NK2 - 1) kh4 = NK2 - 1;
    const int w3 = (2 * t + 3) & 3, w4 = (2 * t + 4) & 3;

    // ---- P1: kk=0, mh=0 ----
    LDB4(s0); LDA4(s0, 0);
    STAGEA(kh3, w3);
    BAR(); WAIT_LGKM0();
    MFMA16(0);
    BAR();
    // ---- P2: kk=0, mh=1 ----
    LDA4(s0, 1);
    STAGEB(kh3, w3);
    BAR(); WAIT_LGKM0();
    MFMA16(1);
    WAIT_VM8();
    BAR();
    // ---- P3: kk=1, mh=0 ----
    LDB4(s1); LDA4(s1, 0);
    STAGEA(kh4, w4);
    BAR(); WAIT_LGKM0();
    MFMA16(0);
    BAR();
    // ---- P4: kk=1, mh=1 ----
    LDA4(s1, 1);
    STAGEB(kh4, w4);
    BAR(); WAIT_LGKM0();
    MFMA16(1);
    WAIT_VM8();
    BAR();
  }
  asm volatile("s_waitcnt vmcnt(0)" ::: "memory");   // drain tail stages into LDS

  // ---- epilogue: f32 LDS staging in 2 row-halves, vectorized global writes ----
  // swizzle byte ^= ((row>>2)&1)<<6 keeps ds_write ~2-way and ds_read linear-ish.
  #pragma unroll
  for (int h = 0; h < 2; ++h) {
    BAR();                       // LDS free (prev phase/main loop fully done)
    if (wr == h) {
      #pragma unroll
      for (int mf = 0; mf < 8; ++mf)
        #pragma unroll
        for (int j = 0; j < 4; ++j)
          #pragma unroll
          for (int r = 0; r < 4; ++r) {
            int row = mf * 16 + lq * 4 + r;                  // 0..127
            int col = wc * 64 + j * 16 + l15;                // 0..255
            int byt = (row * 1024 + col * 4) ^ (((row >> 2) & 1) << 6);
            *(float*)((char*)lds + byt) = acc[mf][j][r];
          }
    }
    WAIT_LGKM0();
    BAR();
    #pragma unroll
    for (int k = 0; k < 8; ++k) {
      int c = tid + k * 512;                                  // 4096 chunk32s
      int row = c >> 5, c32 = c & 31;
      int byt = (row * 1024 + c32 * 32) ^ (((row >> 2) & 1) << 6);
      f32x4 v0 = *(const f32x4*)((const char*)lds + byt);
      f32x4 v1 = *(const f32x4*)((const char*)lds + byt + 16);
      int gcol = bn + c32 * 8;
      size_t off = (size_t)(bm + h * 128 + row) * ldc + gcol;
      if (BIAS) {
        f32x4 bb0 = *(const f32x4*)(bias + gcol);
        f32x4 bb1 = *(const f32x4*)(bias + gcol + 4);
        #pragma unroll
        for (int i = 0; i < 4; ++i) { v0[i] += bb0[i]; v1[i] += bb1[i]; }
      }
      u16x8 ob;
      if (ACC) {
        u16x8 cr = *(const u16x8*)(Cb + off);
        #pragma unroll
        for (int i = 0; i < 4; ++i) {
          ob[i]     = f2b(v0[i] + b2f(cr[i]));
          ob[4 + i] = f2b(v1[i] + b2f(cr[4 + i]));
        }
      } else {
        #pragma unroll
        for (int i = 0; i < 4; ++i) { ob[i] = f2b(v0[i]); ob[4 + i] = f2b(v1[i]); }
      }
      *(u16x8*)(Cb + off) = ob;
    }
  }
#undef STAGEA
#undef STAGEB
#undef LDA4
#undef LDB4
#undef MFMA16
}

// ---------------- attention: one block per (b, head), S=64, DK=64 ----------------
template<int CAUSAL>
__global__ __launch_bounds__(256) void attn_kernel(
    u16* Q, const u16* __restrict__ Kb, const u16* __restrict__ Vb,
    const int* __restrict__ mask, int qld, int kvld) {
  __shared__ u16 Ks[64 * 72];
  __shared__ u16 Vt[64 * 72];
  __shared__ u16 Ps[4][16 * 72];
  const int bh = blockIdx.x;
  const int b = bh >> 3, h = bh & 7;
  const int h0 = h * 64;
  const int tid = threadIdx.x, lane = tid & 63, w = tid >> 6;
  const size_t qbase = (size_t)b * 64 * qld + h0;
  const size_t kbase = (size_t)b * 64 * kvld + h0;
  const int l15 = lane & 15, l16 = (lane >> 4) * 8;

  {
    int r = tid >> 2;
    int c = (tid & 3) * 16;
    const u16* ksrc = Kb + kbase + (size_t)r * kvld + c;
    *(u16x8*)&Ks[r * 72 + c]     = *(const u16x8*)ksrc;
    *(u16x8*)&Ks[r * 72 + c + 8] = *(const u16x8*)(ksrc + 8);
    const u16* vsrc = Vb + kbase + (size_t)r * kvld + c;
    u16x8 t0 = *(const u16x8*)vsrc;
    u16x8 t1 = *(const u16x8*)(vsrc + 8);
    #pragma unroll
    for (int i = 0; i < 8; ++i) {
      Vt[(c + i) * 72 + r]     = t0[i];
      Vt[(c + 8 + i) * 72 + r] = t1[i];
    }
  }
  const int qrow = w * 16 + l15;
  const u16* qp = Q + qbase + (size_t)qrow * qld;
  bf16x8 qf0 = *(const bf16x8*)&qp[l16];
  bf16x8 qf1 = *(const bf16x8*)&qp[32 + l16];
  __syncthreads();

  f32x4 sc[4] = {};
  #pragma unroll
  for (int nf = 0; nf < 4; ++nf) {
    bf16x8 k0 = *(const bf16x8*)&Ks[(nf * 16 + l15) * 72 + l16];
    bf16x8 k1 = *(const bf16x8*)&Ks[(nf * 16 + l15) * 72 + 32 + l16];
    sc[nf] = mfma16(qf0, k0, sc[nf]);
    sc[nf] = mfma16(qf1, k1, sc[nf]);
  }
  int mk[4];
  #pragma unroll
  for (int nf = 0; nf < 4; ++nf) mk[nf] = mask[b * 64 + nf * 16 + l15];
  float pv[4][4];
  #pragma unroll
  for (int r = 0; r < 4; ++r) {
    int q = w * 16 + (lane >> 4) * 4 + r;
    #pragma unroll
    for (int nf = 0; nf < 4; ++nf) {
      int k = nf * 16 + l15;
      bool kp = (mk[nf] != 0);
      if (CAUSAL) kp = kp && (k <= q);
      pv[r][nf] = kp ? sc[nf][r] * 0.125f : -1e9f;
    }
  }
  #pragma unroll
  for (int r = 0; r < 4; ++r) {
    float mx = fmaxf(fmaxf(pv[r][0], pv[r][1]), fmaxf(pv[r][2], pv[r][3]));
    #pragma unroll
    for (int off = 1; off < 16; off <<= 1) mx = fmaxf(mx, __shfl_xor(mx, off));
    float sum = 0.f;
    #pragma unroll
    for (int nf = 0; nf < 4; ++nf) { pv[r][nf] = __expf(pv[r][nf] - mx); sum += pv[r][nf]; }
    #pragma unroll
    for (int off = 1; off < 16; off <<= 1) sum += __shfl_xor(sum, off);
    float inv = 1.0f / sum;
    #pragma unroll
    for (int nf = 0; nf < 4; ++nf) pv[r][nf] *= inv;
  }
  #pragma unroll
  for (int r = 0; r < 4; ++r) {
    int q = (lane >> 4) * 4 + r;
    #pragma unroll
    for (int nf = 0; nf < 4; ++nf)
      Ps[w][q * 72 + nf * 16 + l15] = f2b(pv[r][nf]);
  }
  f32x4 oacc[4] = {};
  #pragma unroll
  for (int kk = 0; kk < 2; ++kk) {
    bf16x8 pa = *(const bf16x8*)&Ps[w][l15 * 72 + kk * 32 + l16];
    #pragma unroll
    for (int df = 0; df < 4; ++df) {
      bf16x8 vf = *(const bf16x8*)&Vt[(df * 16 + l15) * 72 + kk * 32 + l16];
      oacc[df] = mfma16(pa, vf, oacc[df]);
    }
  }
  #pragma unroll
  for (int df = 0; df < 4; ++df) {
    int col = df * 16 + l15;
    #pragma unroll
    for (int r = 0; r < 4; ++r) {
      int t = w * 16 + (lane >> 4) * 4 + r;
      Q[qbase + (size_t)t * qld + col] = f2b(oacc[df][r]);
    }
  }
}

// ---------------- host side ----------------
extern "C" void kernel_launch(void* const* d_in, const int* in_sizes, int n_in,
                              void* d_out, int out_size, void* d_ws, size_t ws_size,
                              hipStream_t stream) {
  const int* src_ids    = (const int*)d_in[0];
  const int* tgt_ids    = (const int*)d_in[1];
  const int* src_mask   = (const int*)d_in[2];
  const int* tgt_mask   = (const int*)d_in[3];
  const float* src_emb  = (const float*)d_in[4];
  const float* tgt_emb  = (const float*)d_in[5];
  const float* enc_wq = (const float*)d_in[6];
  const float* enc_wk = (const float*)d_in[7];
  const float* enc_wv = (const float*)d_in[8];
  const float* enc_wo = (const float*)d_in[9];
  const float* enc_g  = (const float*)d_in[10];
  const float* enc_b  = (const float*)d_in[11];
  const float* fc1w = (const float*)d_in[12];
  const float* fc1b = (const float*)d_in[13];
  const float* fc2w = (const float*)d_in[14];
  const float* fc2b = (const float*)d_in[15];
  const float* mwq = (const float*)d_in[16];
  const float* mwk = (const float*)d_in[17];
  const float* mwv = (const float*)d_in[18];
  const float* mwo = (const float*)d_in[19];
  const float* cwq = (const float*)d_in[20];
  const float* cwo = (const float*)d_in[21];
  const float* dec_g = (const float*)d_in[22];
  const float* dec_b = (const float*)d_in[23];
  const float* dfw = (const float*)d_in[24];
  const float* dfb = (const float*)d_in[25];
  float* outF = (float*)d_out;
  u16* kvenc = (u16*)d_out;   // encoder [K|V] dense [T,1024] parked in d_out (64 MB)

  constexpr size_t SZ_PE  = (size_t)SLEN * HD * 4;
  constexpr size_t SZ_W   = (size_t)114 * EW * 2;
  constexpr size_t SZ_CUR = (size_t)TTOK * HD * 2;            // 32 MB
  constexpr size_t SZ_QKV = (size_t)TTOK * 1536 * 2;          // 96 MB
  constexpr size_t NEED   = SZ_PE + SZ_W + SZ_CUR + SZ_QKV;
  if (ws_size < NEED) return;

  char* ws = (char*)d_ws;
  float* pe = (float*)ws;
  u16* W    = (u16*)(ws + SZ_PE);
  u16* cur  = (u16*)(ws + SZ_PE + SZ_W);
  u16* qkv  = (u16*)(ws + SZ_PE + SZ_W + SZ_CUR);
  u16* z2   = qkv + (size_t)TTOK * 1024;

  dim3 blk(256), blk5(512);
  const unsigned int E = EW, S_E = 12 * EW, S_D = 7 * EW;
  u16* WD = W + (size_t)72 * EW;

  pe_kernel<<<128, blk, 0, stream>>>(pe);

  wconv_kernel<<<768,  blk, 0, stream>>>(enc_wq, W,          E,     S_E);
  wconv_kernel<<<768,  blk, 0, stream>>>(enc_wk, W + E,      E,     S_E);
  wconv_kernel<<<768,  blk, 0, stream>>>(enc_wv, W + 2 * E,  E,     S_E);
  wconv_kernel<<<768,  blk, 0, stream>>>(enc_wo, W + 3 * E,  E,     S_E);
  wconv_kernel<<<3072, blk, 0, stream>>>(fc1w,   W + 4 * E,  4 * E, S_E);
  wconv_kernel<<<3072, blk, 0, stream>>>(fc2w,   W + 8 * E,  4 * E, S_E);
  wconv_kernel<<<768,  blk, 0, stream>>>(mwq,    WD,         E,     S_D);
  wconv_kernel<<<768,  blk, 0, stream>>>(mwk,    WD + E,     E,     S_D);
  wconv_kernel<<<768,  blk, 0, stream>>>(mwv,    WD + 2 * E, E,     S_D);
  wconv_kernel<<<768,  blk, 0, stream>>>(mwo,    WD + 3 * E, E,     S_D);
  wconv_kernel<<<768,  blk, 0, stream>>>(cwq,    WD + 4 * E, E,     S_D);
  wconv_kernel<<<768,  blk, 0, stream>>>(cwo,    WD + 5 * E, E,     S_D);
  wconv_kernel<<<768,  blk, 0, stream>>>(dfw,    WD + 6 * E, E,     S_D);

  // ---------------- encoder ----------------
  embed_kernel<<<8192, blk, 0, stream>>>(src_ids, src_emb, pe, cur);
  for (int l = 0; l < 6; ++l) {
    const u16* Wl = W + (size_t)l * S_E;
    const float* g  = enc_g + (size_t)l * HD;
    const float* bb = enc_b + (size_t)l * HD;
    const float* b1 = fc1b + (size_t)l * FFD;
    const float* b2 = fc2b + (size_t)l * HD;

    gemm256<0,0><<<768, blk5, 0, stream>>>(cur, Wl, nullptr, qkv, 6, 512, 512, 512, 1536);
    attn_kernel<0><<<4096, blk, 0, stream>>>(qkv, qkv + 512, qkv + 1024, src_mask, 1536, 1536);
    if (l == 5)
      kvsave_kernel<<<16384, blk, 0, stream>>>(qkv, kvenc);
    gemm256<0,0><<<256, blk5, 0, stream>>>(qkv, Wl + 3 * E, nullptr, qkv + 1024, 2, 512, 1536, 512, 1536);
    ln_kernel<0><<<8192, blk, 0, stream>>>(cur, qkv + 1024, 1536, g, bb, cur, nullptr);
    gemm256<1,0><<<512, blk5, 0, stream>>>(cur, Wl + 4 * E, b1,        qkv, 4, 512, 512, 512, 1024);
    gemm256<1,0><<<256, blk5, 0, stream>>>(qkv, Wl + 8 * E, b2,        z2,  2, 1024, 1024, 2048, 512);
    gemm256<1,0><<<512, blk5, 0, stream>>>(cur, Wl + 6 * E, b1 + 1024, qkv, 4, 512, 512, 512, 1024);
    gemm256<0,1><<<256, blk5, 0, stream>>>(qkv, Wl + 8 * E + 1024, nullptr, z2, 2, 1024, 1024, 2048, 512);
    ln_kernel<0><<<8192, blk, 0, stream>>>(cur, z2, 512, g, bb, cur, nullptr);
  }

  // ---------------- decoder ----------------
  embed_kernel<<<8192, blk, 0, stream>>>(tgt_ids, tgt_emb, pe, cur);
  for (int l = 0; l < 6; ++l) {
    const u16* Wl = WD + (size_t)l * S_D;
    const float* g  = dec_g + (size_t)l * HD;
    const float* bb = dec_b + (size_t)l * HD;
    const float* fb = dfb + (size_t)l * HD;

    gemm256<0,0><<<768, blk5, 0, stream>>>(cur, Wl, nullptr, qkv, 6, 512, 512, 512, 1536);
    attn_kernel<1><<<4096, blk, 0, stream>>>(qkv, qkv + 512, qkv + 1024, tgt_mask, 1536, 1536);
    gemm256<0,0><<<256, blk5, 0, stream>>>(qkv, Wl + 3 * E, nullptr, qkv + 1024, 2, 512, 1536, 512, 1536);
    ln_kernel<0><<<8192, blk, 0, stream>>>(cur, qkv + 1024, 1536, g, bb, cur, nullptr);

    gemm256<0,0><<<256, blk5, 0, stream>>>(cur, Wl + 4 * E, nullptr, qkv, 2, 512, 512, 512, 1536);
    attn_kernel<1><<<4096, blk, 0, stream>>>(qkv, kvenc, kvenc + 512, tgt_mask, 1536, 1024);
    gemm256<0,0><<<256, blk5, 0, stream>>>(qkv, Wl + 5 * E, nullptr, qkv + 1024, 2, 512, 1536, 512, 1536);
    ln_kernel<0><<<8192, blk, 0, stream>>>(cur, qkv + 1024, 1536, g, bb, cur, nullptr);

    gemm256<1,0><<<256, blk5, 0, stream>>>(cur, Wl + 6 * E, fb, qkv, 2, 512, 512, 512, 512);
    if (l == 5)
      ln_kernel<1><<<8192, blk, 0, stream>>>(cur, qkv, 512, g, bb, nullptr, outF);
    else
      ln_kernel<0><<<8192, blk, 0, stream>>>(cur, qkv, 512, g, bb, cur, nullptr);
  }
  (void)in_sizes; (void)n_in; (void)out_size;
}

// Round 7
// 3527.765 us; speedup vs baseline: 1.7012x; 1.0146x over previous
//
#include <hip/hip_runtime.h>

typedef unsigned short u16;
typedef u16 u16x8 __attribute__((ext_vector_type(8)));
typedef __bf16 bf16x8 __attribute__((ext_vector_type(8)));
typedef float f32x4 __attribute__((ext_vector_type(4)));

#define TTOK 32768
#define HD 512
#define FFD 2048
#define SLEN 64
#define EW 262144            // 512*512 elems

__device__ __forceinline__ float b2f(u16 u) {
  union { float f; unsigned int i; } v; v.i = ((unsigned int)u) << 16; return v.f;
}
__device__ __forceinline__ u16 f2b(float f) {
  union { float f; unsigned int i; } v; v.f = f;
  unsigned int i = v.i;
  return (u16)((i + 0x7FFFu + ((i >> 16) & 1u)) >> 16);  // RNE
}

__device__ __forceinline__ void gload16(const u16* g, u16* l) {
  __builtin_amdgcn_global_load_lds((const __attribute__((address_space(1))) void*)g,
                                   (__attribute__((address_space(3))) void*)l,
                                   16, 0, 0);
}

__device__ __forceinline__ f32x4 mfma16(bf16x8 a, bf16x8 b, f32x4 c) {
  return __builtin_amdgcn_mfma_f32_16x16x32_bf16(a, b, c, 0, 0, 0);
}

// ---------------- positional encoding table [S,H] f32 ----------------
__global__ __launch_bounds__(256) void pe_kernel(float* __restrict__ pe) {
  int idx = blockIdx.x * 256 + threadIdx.x;
  int s = idx >> 9, h = idx & 511;
  float e2i = (float)(h & ~1);
  float ang = (float)s * powf(10000.0f, -e2i * (1.0f / 512.0f));
  pe[idx] = (h & 1) ? cosf(ang) : sinf(ang);
}

// ------------- weight convert f32 -> bf16, per-layer strided dest -------------
__global__ __launch_bounds__(256) void wconv_kernel(
    const float* __restrict__ src, u16* __restrict__ dst,
    unsigned int npl, unsigned int dstride) {
  size_t i = ((size_t)blockIdx.x * 256 + threadIdx.x) * 8;
  unsigned int l = (unsigned int)(i / npl);
  unsigned int r = (unsigned int)(i - (size_t)l * npl);
  f32x4 a = *(const f32x4*)(src + i), b = *(const f32x4*)(src + i + 4);
  u16x8 o;
  #pragma unroll
  for (int k = 0; k < 4; ++k) { o[k] = f2b(a[k]); o[4 + k] = f2b(b[k]); }
  *(u16x8*)(dst + (size_t)l * dstride + r) = o;
}

// ---------------- embedding (f32) + PE (f32) -> bf16 ----------------
__global__ __launch_bounds__(256) void embed_kernel(
    const int* __restrict__ ids, const float* __restrict__ emb,
    const float* __restrict__ pe, u16* __restrict__ outB) {
  int chunk = blockIdx.x * 256 + threadIdx.x;
  int t = chunk >> 6;
  int c8 = (chunk & 63) * 8;
  int s = t & (SLEN - 1);
  int id = ids[t];
  const float* e = emb + (size_t)id * HD + c8;
  const float* p = pe + s * HD + c8;
  f32x4 e0 = *(const f32x4*)e, e1 = *(const f32x4*)(e + 4);
  f32x4 p0 = *(const f32x4*)p, p1 = *(const f32x4*)(p + 4);
  u16x8 ob;
  #pragma unroll
  for (int i = 0; i < 4; ++i) {
    ob[i]     = f2b(e0[i] + p0[i]);
    ob[4 + i] = f2b(e1[i] + p1[i]);
  }
  *(u16x8*)(outB + (size_t)t * HD + c8) = ob;
}

// ---------------- residual + layernorm (bf16 in, f32 params) ----------------
template<int F32OUT>
__global__ __launch_bounds__(256) void ln_kernel(
    const u16* A, const u16* __restrict__ Z, int ldz,
    const float* __restrict__ g, const float* __restrict__ b,
    u16* outB, float* outF) {
  int row = blockIdx.x * 4 + (threadIdx.x >> 6);
  int lane = threadIdx.x & 63;
  size_t base = (size_t)row * HD + lane * 8;
  size_t zbase = (size_t)row * ldz + lane * 8;
  u16x8 av = *(const u16x8*)(A + base);
  u16x8 zv = *(const u16x8*)(Z + zbase);
  float x[8];
  float s = 0.f;
  #pragma unroll
  for (int i = 0; i < 8; ++i) { x[i] = b2f(av[i]) + b2f(zv[i]); s += x[i]; }
  #pragma unroll
  for (int off = 32; off; off >>= 1) s += __shfl_xor(s, off);
  float m = s * (1.0f / HD);
  float vs = 0.f;
  #pragma unroll
  for (int i = 0; i < 8; ++i) { float d = x[i] - m; vs += d * d; }
  #pragma unroll
  for (int off = 32; off; off >>= 1) vs += __shfl_xor(vs, off);
  float rstd = rsqrtf(vs * (1.0f / HD) + 1e-5f);
  f32x4 g0 = *(const f32x4*)(g + lane * 8), g1 = *(const f32x4*)(g + lane * 8 + 4);
  f32x4 b0 = *(const f32x4*)(b + lane * 8), b1 = *(const f32x4*)(b + lane * 8 + 4);
  float o[8];
  #pragma unroll
  for (int i = 0; i < 4; ++i) {
    o[i]     = (x[i] - m) * rstd * g0[i] + b0[i];
    o[4 + i] = (x[4 + i] - m) * rstd * g1[i] + b1[i];
  }
  if (F32OUT) {
    f32x4 o0, o1;
    #pragma unroll
    for (int i = 0; i < 4; ++i) { o0[i] = o[i]; o1[i] = o[4 + i]; }
    *(f32x4*)(outF + base) = o0;
    *(f32x4*)(outF + base + 4) = o1;
  } else {
    u16x8 ob;
    #pragma unroll
    for (int i = 0; i < 8; ++i) ob[i] = f2b(o[i]);
    *(u16x8*)(outB + base) = ob;
  }
}

// ===================== 256x256 8-phase pipelined bf16 NT GEMM =====================
#define BAR() __builtin_amdgcn_s_barrier()
#define WAIT_LGKM0() asm volatile("s_waitcnt lgkmcnt(0)" ::: "memory")
#define WAIT_VM8()   asm volatile("s_waitcnt vmcnt(8)" ::: "memory")

template<int BIAS, int ACC>
__global__ __launch_bounds__(512, 2) void gemm256(
    const u16* __restrict__ A, const u16* __restrict__ Bw,
    const float* __restrict__ bias, u16* __restrict__ Cb,
    int nbn, int K, int lda, int ldb, int ldc) {
  __shared__ u16 lds[65536];               // 128 KB
  const int tid = threadIdx.x;
  const int lane = tid & 63, w = tid >> 6;
  const int wr = w >> 2, wc = w & 3;
  const int l15 = lane & 15, lq = lane >> 4;

  const int cpx = gridDim.x >> 3;
  const int L = (blockIdx.x & 7) * cpx + (blockIdx.x >> 3);
  const int bm = (L / nbn) * 256, bn = (L % nbn) * 256;

  const u16 *pa0, *pa1, *pb0, *pb1;
  {
    int p0 = w * 1024 + lane * 16;
    int p1 = p0 + 8192;
    int lb0 = p0 ^ (((p0 >> 7) & 7) << 4);
    int lb1 = p1 ^ (((p1 >> 7) & 7) << 4);
    int r0 = (lb0 >> 7) + (((lb0 >> 6) & 1) << 7);
    int r1 = (lb1 >> 7) + (((lb1 >> 6) & 1) << 7);
    int c0 = (lb0 & 63) >> 1;
    int c1 = (lb1 & 63) >> 1;
    pa0 = A  + (size_t)(bm + r0) * lda + c0;
    pa1 = A  + (size_t)(bm + r1) * lda + c1;
    pb0 = Bw + (size_t)(bn + r0) * ldb + c0;
    pb1 = Bw + (size_t)(bn + r1) * ldb + c1;
  }
  const int dst = w * 512;

  int offA[8], offB[4];
  #pragma unroll
  for (int mf = 0; mf < 8; ++mf) {
    int rowp = mf * 16 + l15;
    offA[mf] = ((rowp * 128 + wr * 64 + lq * 16) ^ ((l15 & 7) << 4)) >> 1;
  }
  #pragma unroll
  for (int j = 0; j < 4; ++j) {
    int rB = wc * 64 + j * 16 + l15;
    int rowp = rB & 127, cg = rB >> 7;
    offB[j] = ((rowp * 128 + cg * 64 + lq * 16) ^ ((l15 & 7) << 4)) >> 1;
  }

  const int NK2 = K >> 5;
  const int NT  = K >> 6;

#define STAGEA(kh, slot) { \
    gload16(pa0 + (kh) * 32, &lds[(slot) * 8192 + dst]); \
    gload16(pa1 + (kh) * 32, &lds[(slot) * 8192 + dst + 4096]); }
#define STAGEB(kh, slot) { \
    gload16(pb0 + (kh) * 32, &lds[32768 + (slot) * 8192 + dst]); \
    gload16(pb1 + (kh) * 32, &lds[32768 + (slot) * 8192 + dst + 4096]); }
#define LDA4(slot, mh) { \
    _Pragma("unroll") for (int i = 0; i < 4; ++i) \
      af[i] = *(const bf16x8*)&lds[(slot) * 8192 + offA[(mh) * 4 + i]]; }
#define LDB4(slot) { \
    _Pragma("unroll") for (int j = 0; j < 4; ++j) \
      bf[j] = *(const bf16x8*)&lds[32768 + (slot) * 8192 + offB[j]]; }
#define MFMA16(mh) { \
    __builtin_amdgcn_s_setprio(1); \
    _Pragma("unroll") for (int i = 0; i < 4; ++i) \
      _Pragma("unroll") for (int j = 0; j < 4; ++j) \
        acc[(mh) * 4 + i][j] = mfma16(af[i], bf[j], acc[(mh) * 4 + i][j]); \
    __builtin_amdgcn_s_setprio(0); }

  f32x4 acc[8][4] = {};
  bf16x8 af[4], bf[4];

  STAGEA(0, 0); STAGEB(0, 0);
  STAGEA(1, 1); STAGEB(1, 1);
  STAGEA(2, 2); STAGEB(2, 2);
  WAIT_VM8();
  BAR();

  for (int t = 0; t < NT; ++t) {
    const int s0 = (2 * t) & 3, s1 = (2 * t + 1) & 3;
    int kh3 = 2 * t + 3; if (kh3 > NK2 - 1) kh3 = NK2 - 1;
    int kh4 = 2 * t + 4; if (kh4 > NK2 - 1) kh4 = NK2 - 1;
    const int w3 = (2 * t + 3) & 3, w4 = (2 * t + 4) & 3;

    LDB4(s0); LDA4(s0, 0);
    STAGEA(kh3, w3);
    BAR(); WAIT_LGKM0();
    MFMA16(0);
    BAR();

    LDA4(s0, 1);
    STAGEB(kh3, w3);
    BAR(); WAIT_LGKM0();
    MFMA16(1);
    WAIT_VM8();
    BAR();

    LDB4(s1); LDA4(s1, 0);
    STAGEA(kh4, w4);
    BAR(); WAIT_LGKM0();
    MFMA16(0);
    BAR();

    LDA4(s1, 1);
    STAGEB(kh4, w4);
    BAR(); WAIT_LGKM0();
    MFMA16(1);
    WAIT_VM8();
    BAR();
  }
  asm volatile("s_waitcnt vmcnt(0)" ::: "memory");

  // ---- epilogue: f32 LDS staging in 2 row-halves, vectorized global writes ----
  #pragma unroll
  for (int h = 0; h < 2; ++h) {
    BAR();
    if (wr == h) {
      #pragma unroll
      for (int mf = 0; mf < 8; ++mf)
        #pragma unroll
        for (int j = 0; j < 4; ++j)
          #pragma unroll
          for (int r = 0; r < 4; ++r) {
            int row = mf * 16 + lq * 4 + r;
            int col = wc * 64 + j * 16 + l15;
            int byt = (row * 1024 + col * 4) ^ (((row >> 2) & 1) << 6);
            *(float*)((char*)lds + byt) = acc[mf][j][r];
          }
    }
    WAIT_LGKM0();
    BAR();
    #pragma unroll
    for (int k = 0; k < 8; ++k) {
      int c = tid + k * 512;
      int row = c >> 5, c32 = c & 31;
      int byt = (row * 1024 + c32 * 32) ^ (((row >> 2) & 1) << 6);
      f32x4 v0 = *(const f32x4*)((const char*)lds + byt);
      f32x4 v1 = *(const f32x4*)((const char*)lds + byt + 16);
      int gcol = bn + c32 * 8;
      size_t off = (size_t)(bm + h * 128 + row) * ldc + gcol;
      if (BIAS) {
        f32x4 bb0 = *(const f32x4*)(bias + gcol);
        f32x4 bb1 = *(const f32x4*)(bias + gcol + 4);
        #pragma unroll
        for (int i = 0; i < 4; ++i) { v0[i] += bb0[i]; v1[i] += bb1[i]; }
      }
      u16x8 ob;
      if (ACC) {
        u16x8 cr = *(const u16x8*)(Cb + off);
        #pragma unroll
        for (int i = 0; i < 4; ++i) {
          ob[i]     = f2b(v0[i] + b2f(cr[i]));
          ob[4 + i] = f2b(v1[i] + b2f(cr[4 + i]));
        }
      } else {
        #pragma unroll
        for (int i = 0; i < 4; ++i) { ob[i] = f2b(v0[i]); ob[4 + i] = f2b(v1[i]); }
      }
      *(u16x8*)(Cb + off) = ob;
    }
  }
#undef STAGEA
#undef STAGEB
#undef LDA4
#undef LDB4
#undef MFMA16
}

// ---------------- attention: one block per (b, head), S=64, DK=64 ----------------
// SAVEKV: also write K,V slices dense into kvdst [T,1024] (K cols 0-511, V 512-1023).
template<int CAUSAL, int SAVEKV>
__global__ __launch_bounds__(256) void attn_kernel(
    u16* Q, const u16* __restrict__ Kb, const u16* __restrict__ Vb,
    const int* __restrict__ mask, int qld, int kvld, u16* __restrict__ kvdst) {
  __shared__ u16 Ks[64 * 72];
  __shared__ u16 Vt[64 * 72];
  __shared__ u16 Ps[4][16 * 72];
  const int bh = blockIdx.x;
  const int b = bh >> 3, h = bh & 7;
  const int h0 = h * 64;
  const int tid = threadIdx.x, lane = tid & 63, w = tid >> 6;
  const size_t qbase = (size_t)b * 64 * qld + h0;
  const size_t kbase = (size_t)b * 64 * kvld + h0;
  const int l15 = lane & 15, l16 = (lane >> 4) * 8;

  {
    int r = tid >> 2;
    int c = (tid & 3) * 16;
    const u16* ksrc = Kb + kbase + (size_t)r * kvld + c;
    u16x8 k0 = *(const u16x8*)ksrc;
    u16x8 k1 = *(const u16x8*)(ksrc + 8);
    *(u16x8*)&Ks[r * 72 + c]     = k0;
    *(u16x8*)&Ks[r * 72 + c + 8] = k1;
    const u16* vsrc = Vb + kbase + (size_t)r * kvld + c;
    u16x8 t0 = *(const u16x8*)vsrc;
    u16x8 t1 = *(const u16x8*)(vsrc + 8);
    #pragma unroll
    for (int i = 0; i < 8; ++i) {
      Vt[(c + i) * 72 + r]     = t0[i];
      Vt[(c + 8 + i) * 72 + r] = t1[i];
    }
    if (SAVEKV) {
      size_t db = (size_t)(b * 64 + r) * 1024 + h0 + c;
      *(u16x8*)(kvdst + db)       = k0;
      *(u16x8*)(kvdst + db + 8)   = k1;
      *(u16x8*)(kvdst + db + 512) = t0;
      *(u16x8*)(kvdst + db + 520) = t1;
    }
  }
  const int qrow = w * 16 + l15;
  const u16* qp = Q + qbase + (size_t)qrow * qld;
  bf16x8 qf0 = *(const bf16x8*)&qp[l16];
  bf16x8 qf1 = *(const bf16x8*)&qp[32 + l16];
  __syncthreads();

  f32x4 sc[4] = {};
  #pragma unroll
  for (int nf = 0; nf < 4; ++nf) {
    bf16x8 k0 = *(const bf16x8*)&Ks[(nf * 16 + l15) * 72 + l16];
    bf16x8 k1 = *(const bf16x8*)&Ks[(nf * 16 + l15) * 72 + 32 + l16];
    sc[nf] = mfma16(qf0, k0, sc[nf]);
    sc[nf] = mfma16(qf1, k1, sc[nf]);
  }
  int mk[4];
  #pragma unroll
  for (int nf = 0; nf < 4; ++nf) mk[nf] = mask[b * 64 + nf * 16 + l15];
  float pv[4][4];
  #pragma unroll
  for (int r = 0; r < 4; ++r) {
    int q = w * 16 + (lane >> 4) * 4 + r;
    #pragma unroll
    for (int nf = 0; nf < 4; ++nf) {
      int k = nf * 16 + l15;
      bool kp = (mk[nf] != 0);
      if (CAUSAL) kp = kp && (k <= q);
      pv[r][nf] = kp ? sc[nf][r] * 0.125f : -1e9f;
    }
  }
  #pragma unroll
  for (int r = 0; r < 4; ++r) {
    float mx = fmaxf(fmaxf(pv[r][0], pv[r][1]), fmaxf(pv[r][2], pv[r][3]));
    #pragma unroll
    for (int off = 1; off < 16; off <<= 1) mx = fmaxf(mx, __shfl_xor(mx, off));
    float sum = 0.f;
    #pragma unroll
    for (int nf = 0; nf < 4; ++nf) { pv[r][nf] = __expf(pv[r][nf] - mx); sum += pv[r][nf]; }
    #pragma unroll
    for (int off = 1; off < 16; off <<= 1) sum += __shfl_xor(sum, off);
    float inv = 1.0f / sum;
    #pragma unroll
    for (int nf = 0; nf < 4; ++nf) pv[r][nf] *= inv;
  }
  #pragma unroll
  for (int r = 0; r < 4; ++r) {
    int q = (lane >> 4) * 4 + r;
    #pragma unroll
    for (int nf = 0; nf < 4; ++nf)
      Ps[w][q * 72 + nf * 16 + l15] = f2b(pv[r][nf]);
  }
  f32x4 oacc[4] = {};
  #pragma unroll
  for (int kk = 0; kk < 2; ++kk) {
    bf16x8 pa = *(const bf16x8*)&Ps[w][l15 * 72 + kk * 32 + l16];
    #pragma unroll
    for (int df = 0; df < 4; ++df) {
      bf16x8 vf = *(const bf16x8*)&Vt[(df * 16 + l15) * 72 + kk * 32 + l16];
      oacc[df] = mfma16(pa, vf, oacc[df]);
    }
  }
  #pragma unroll
  for (int df = 0; df < 4; ++df) {
    int col = df * 16 + l15;
    #pragma unroll
    for (int r = 0; r < 4; ++r) {
      int t = w * 16 + (lane >> 4) * 4 + r;
      Q[qbase + (size_t)t * qld + col] = f2b(oacc[df][r]);
    }
  }
}

// ---------------- host side ----------------
extern "C" void kernel_launch(void* const* d_in, const int* in_sizes, int n_in,
                              void* d_out, int out_size, void* d_ws, size_t ws_size,
                              hipStream_t stream) {
  const int* src_ids    = (const int*)d_in[0];
  const int* tgt_ids    = (const int*)d_in[1];
  const int* src_mask   = (const int*)d_in[2];
  const int* tgt_mask   = (const int*)d_in[3];
  const float* src_emb  = (const float*)d_in[4];
  const float* tgt_emb  = (const float*)d_in[5];
  const float* enc_wq = (const float*)d_in[6];
  const float* enc_wk = (const float*)d_in[7];
  const float* enc_wv = (const float*)d_in[8];
  const float* enc_wo = (const float*)d_in[9];
  const float* enc_g  = (const float*)d_in[10];
  const float* enc_b  = (const float*)d_in[11];
  const float* fc1w = (const float*)d_in[12];
  const float* fc1b = (const float*)d_in[13];
  const float* fc2w = (const float*)d_in[14];
  const float* fc2b = (const float*)d_in[15];
  const float* mwq = (const float*)d_in[16];
  const float* mwk = (const float*)d_in[17];
  const float* mwv = (const float*)d_in[18];
  const float* mwo = (const float*)d_in[19];
  const float* cwq = (const float*)d_in[20];
  const float* cwo = (const float*)d_in[21];
  const float* dec_g = (const float*)d_in[22];
  const float* dec_b = (const float*)d_in[23];
  const float* dfw = (const float*)d_in[24];
  const float* dfb = (const float*)d_in[25];
  float* outF = (float*)d_out;
  u16* kvenc = (u16*)d_out;   // encoder [K|V] dense [T,1024] parked in d_out (64 MB)

  constexpr size_t SZ_PE  = (size_t)SLEN * HD * 4;
  constexpr size_t SZ_W   = (size_t)114 * EW * 2;
  constexpr size_t SZ_CUR = (size_t)TTOK * HD * 2;            // 32 MB
  constexpr size_t SZ_QKV = (size_t)TTOK * 1536 * 2;          // 96 MB
  constexpr size_t SZ_R   = (size_t)TTOK * FFD * 2;           // 128 MB (inter/qkv alias)
  constexpr size_t SZ_Z2  = (size_t)TTOK * HD * 2;            // 32 MB
  constexpr size_t NEED_SMALL = SZ_PE + SZ_W + SZ_CUR + SZ_QKV;          // ~185 MiB
  constexpr size_t NEED_BIG   = SZ_PE + SZ_W + SZ_CUR + SZ_R + SZ_Z2;    // ~249 MiB
  if (ws_size < NEED_SMALL) return;
  const bool big = (ws_size >= NEED_BIG);

  char* ws = (char*)d_ws;
  float* pe = (float*)ws;
  u16* W    = (u16*)(ws + SZ_PE);
  u16* cur  = (u16*)(ws + SZ_PE + SZ_W);
  u16* qkv  = (u16*)(ws + SZ_PE + SZ_W + SZ_CUR);             // also inter (big)
  u16* z2   = big ? (u16*)(ws + SZ_PE + SZ_W + SZ_CUR + SZ_R)
                  : qkv + (size_t)TTOK * 1024;

  dim3 blk(256), blk5(512);
  const unsigned int E = EW, S_E = 12 * EW, S_D = 7 * EW;
  u16* WD = W + (size_t)72 * EW;

  pe_kernel<<<128, blk, 0, stream>>>(pe);

  wconv_kernel<<<768,  blk, 0, stream>>>(enc_wq, W,          E,     S_E);
  wconv_kernel<<<768,  blk, 0, stream>>>(enc_wk, W + E,      E,     S_E);
  wconv_kernel<<<768,  blk, 0, stream>>>(enc_wv, W + 2 * E,  E,     S_E);
  wconv_kernel<<<768,  blk, 0, stream>>>(enc_wo, W + 3 * E,  E,     S_E);
  wconv_kernel<<<3072, blk, 0, stream>>>(fc1w,   W + 4 * E,  4 * E, S_E);
  wconv_kernel<<<3072, blk, 0, stream>>>(fc2w,   W + 8 * E,  4 * E, S_E);
  wconv_kernel<<<768,  blk, 0, stream>>>(mwq,    WD,         E,     S_D);
  wconv_kernel<<<768,  blk, 0, stream>>>(mwk,    WD + E,     E,     S_D);
  wconv_kernel<<<768,  blk, 0, stream>>>(mwv,    WD + 2 * E, E,     S_D);
  wconv_kernel<<<768,  blk, 0, stream>>>(mwo,    WD + 3 * E, E,     S_D);
  wconv_kernel<<<768,  blk, 0, stream>>>(cwq,    WD + 4 * E, E,     S_D);
  wconv_kernel<<<768,  blk, 0, stream>>>(cwo,    WD + 5 * E, E,     S_D);
  wconv_kernel<<<768,  blk, 0, stream>>>(dfw,    WD + 6 * E, E,     S_D);

  // ---------------- encoder ----------------
  embed_kernel<<<8192, blk, 0, stream>>>(src_ids, src_emb, pe, cur);
  for (int l = 0; l < 6; ++l) {
    const u16* Wl = W + (size_t)l * S_E;
    const float* g  = enc_g + (size_t)l * HD;
    const float* bb = enc_b + (size_t)l * HD;
    const float* b1 = fc1b + (size_t)l * FFD;
    const float* b2 = fc2b + (size_t)l * HD;

    gemm256<0,0><<<768, blk5, 0, stream>>>(cur, Wl, nullptr, qkv, 6, 512, 512, 512, 1536);
    if (l == 5)
      attn_kernel<0,1><<<4096, blk, 0, stream>>>(qkv, qkv + 512, qkv + 1024, src_mask, 1536, 1536, kvenc);
    else
      attn_kernel<0,0><<<4096, blk, 0, stream>>>(qkv, qkv + 512, qkv + 1024, src_mask, 1536, 1536, nullptr);
    gemm256<0,0><<<256, blk5, 0, stream>>>(qkv, Wl + 3 * E, nullptr, qkv + 1024, 2, 512, 1536, 512, 1536);
    ln_kernel<0><<<8192, blk, 0, stream>>>(cur, qkv + 1024, 1536, g, bb, cur, nullptr);
    if (big) {
      // fc1: one N=2048 GEMM into full inter; fc2: one K=2048 GEMM (no ACC pass)
      gemm256<1,0><<<1024, blk5, 0, stream>>>(cur, Wl + 4 * E, b1, qkv, 8, 512, 512, 512, 2048);
      gemm256<1,0><<<256,  blk5, 0, stream>>>(qkv, Wl + 8 * E, b2, z2, 2, 2048, 2048, 2048, 512);
    } else {
      gemm256<1,0><<<512, blk5, 0, stream>>>(cur, Wl + 4 * E, b1,        qkv, 4, 512, 512, 512, 1024);
      gemm256<1,0><<<256, blk5, 0, stream>>>(qkv, Wl + 8 * E, b2,        z2,  2, 1024, 1024, 2048, 512);
      gemm256<1,0><<<512, blk5, 0, stream>>>(cur, Wl + 6 * E, b1 + 1024, qkv, 4, 512, 512, 512, 1024);
      gemm256<0,1><<<256, blk5, 0, stream>>>(qkv, Wl + 8 * E + 1024, nullptr, z2, 2, 1024, 1024, 2048, 512);
    }
    ln_kernel<0><<<8192, blk, 0, stream>>>(cur, z2, 512, g, bb, cur, nullptr);
  }

  // ---------------- decoder ----------------
  embed_kernel<<<8192, blk, 0, stream>>>(tgt_ids, tgt_emb, pe, cur);
  for (int l = 0; l < 6; ++l) {
    const u16* Wl = WD + (size_t)l * S_D;
    const float* g  = dec_g + (size_t)l * HD;
    const float* bb = dec_b + (size_t)l * HD;
    const float* fb = dfb + (size_t)l * HD;

    gemm256<0,0><<<768, blk5, 0, stream>>>(cur, Wl, nullptr, qkv, 6, 512, 512, 512, 1536);
    attn_kernel<1,0><<<4096, blk, 0, stream>>>(qkv, qkv + 512, qkv + 1024, tgt_mask, 1536, 1536, nullptr);
    gemm256<0,0><<<256, blk5, 0, stream>>>(qkv, Wl + 3 * E, nullptr, qkv + 1024, 2, 512, 1536, 512, 1536);
    ln_kernel<0><<<8192, blk, 0, stream>>>(cur, qkv + 1024, 1536, g, bb, cur, nullptr);

    gemm256<0,0><<<256, blk5, 0, stream>>>(cur, Wl + 4 * E, nullptr, qkv, 2, 512, 512, 512, 1536);
    attn_kernel<1,0><<<4096, blk, 0, stream>>>(qkv, kvenc, kvenc + 512, tgt_mask, 1536, 1024, nullptr);
    gemm256<0,0><<<256, blk5, 0, stream>>>(qkv, Wl + 5 * E, nullptr, qkv + 1024, 2, 512, 1536, 512, 1536);
    ln_kernel<0><<<8192, blk, 0, stream>>>(cur, qkv + 1024, 1536, g, bb, cur, nullptr);

    gemm256<1,0><<<256, blk5, 0, stream>>>(cur, Wl + 6 * E, fb, qkv, 2, 512, 512, 512, 512);
    if (l == 5)
      ln_kernel<1><<<8192, blk, 0, stream>>>(cur, qkv, 512, g, bb, nullptr, outF);
    else
      ln_kernel<0><<<8192, blk, 0, stream>>>(cur, qkv, 512, g, bb, cur, nullptr);
  }
  (void)in_sizes; (void)n_in; (void)out_size;
}